// Round 9
// baseline (757.256 us; speedup 1.0000x reference)
//
#include <hip/hip_runtime.h>
#include <hip/hip_bf16.h>
#include <stdint.h>

#define B_ 4
#define F_ 1024
#define S_ 2048
#define K_ 7
#define SP_ (S_ + K_ - 1)   // 2054 padded rows (6 zero rows at the front)
#define FC_ 64              // cumsum chunk size
#define NC_ (F_ / FC_)      // 16 chunks
#define FF_ ((size_t)F_ * F_)
#define BFS_ ((size_t)B_ * F_ * S_)
#define BSPF_ ((size_t)B_ * SP_ * F_)

using f32x4 = __attribute__((ext_vector_type(4))) float;
using f32x16 = __attribute__((ext_vector_type(16))) float;
using s16x8 = __attribute__((ext_vector_type(8))) short;
using bf16 = __hip_bfloat16;

// -------- async global->LDS 16B (wave-uniform base + lane*16 semantics) -----
typedef const __attribute__((address_space(1))) void gvoid_t;
typedef __attribute__((address_space(3))) void lvoid_t;
__device__ __forceinline__ void async16(const void* g, void* l) {
    __builtin_amdgcn_global_load_lds((gvoid_t*)g, (lvoid_t*)l, 16, 0, 0);
}

__device__ __forceinline__ float bf2f(unsigned short u) {
    union { unsigned int i; float f; } c; c.i = ((unsigned int)u) << 16; return c.f;
}

#define FENCE() asm volatile("" ::: "memory")
#define BARRIER() do { FENCE(); __builtin_amdgcn_s_barrier(); FENCE(); } while (0)

// ---------------------------------------------------------------------------
__global__ void zero_pads(bf16* xT, bf16* hT, int nh) {
    int i = blockIdx.x * 256 + threadIdx.x;
    const int per = B_ * (K_ - 1) * F_;
    int total = (1 + nh) * per;
    if (i >= total) return;
    int r = i / per, o = i % per;
    int b = o / ((K_ - 1) * F_);
    int rr = o % ((K_ - 1) * F_);
    bf16 z = __float2bfloat16(0.0f);
    if (r == 0) xT[(size_t)b * SP_ * F_ + rr] = z;
    else        hT[(size_t)(r - 1) * BSPF_ + (size_t)b * SP_ * F_ + rr] = z;
}

__global__ void prep_x(const float* __restrict__ inp, const float* __restrict__ pos,
                       bf16* __restrict__ xT) {
    __shared__ bf16 tile[64][66];
    int b = blockIdx.z;
    int f0 = blockIdx.y * 64, s0 = blockIdx.x * 64;
    int tj = threadIdx.x & 63;
    int t4 = threadIdx.x >> 6;
#pragma unroll
    for (int r = 0; r < 16; ++r) {
        int i = r * 4 + t4;
        size_t off = (size_t)(f0 + i) * S_ + s0 + tj;
        float v = inp[(size_t)b * F_ * S_ + off] + pos[off];
        tile[i][tj] = __float2bfloat16(v);
    }
    __syncthreads();
#pragma unroll
    for (int r = 0; r < 16; ++r) {
        int j = r * 4 + t4;
        xT[(size_t)b * SP_ * F_ + (size_t)(6 + s0 + j) * F_ + f0 + tj] = tile[tj][j];
    }
}

// single-weight repack (sequential fallback)
__global__ void wconv(const float* __restrict__ w, bf16* __restrict__ wt) {
    int i = blockIdx.x * 256 + threadIdx.x;
    if (i >= F_ * F_) return;
    const float* src = w + (size_t)i * K_;
#pragma unroll
    for (int t = 0; t < K_; ++t)
        wt[(size_t)t * FF_ + i] = __float2bfloat16(src[t]);
}

// batched 3-weight repack: grid (FF/256, 3)
__global__ void wconv3(const float* __restrict__ w0, const float* __restrict__ w1,
                       const float* __restrict__ w2, bf16* __restrict__ wt) {
    int i = blockIdx.x * 256 + threadIdx.x;
    int z = blockIdx.y;
    const float* w = (z == 0) ? w0 : (z == 1 ? w1 : w2);
    bf16* dst = wt + (size_t)z * 7 * FF_;
    const float* src = w + (size_t)i * K_;
#pragma unroll
    for (int t = 0; t < K_; ++t)
        dst[(size_t)t * FF_ + i] = __float2bfloat16(src[t]);
}

// ---------------------------------------------------------------------------
// 256x256 bf16 conv-GEMM, BK=64, 8-phase schedule, kb-major K-order with
// SHARED B-panel across the 7 taps (tap = shifted LDS read). LDS 144 KiB.
// R9: MFMA shape 16x16x32 -> 32x32x16 (2382 vs 2075 TF ceiling, half the
// issue slots). Barrier/vmcnt/staging schedule byte-identical to the proven
// R6 kernel (297.9 us); only fragment mapping + read addressing changed.
// A/B lane layout: row/col = l&31, k = (l>>5)*8 + e  [analog of verified 16x16]
// C/D: col = lane&31, row = (reg&3)+8*(reg>>2)+4*(lane>>5)  [m74/m101]
#define MFMA_OCT(MB, NB)                                                         \
    __builtin_amdgcn_s_setprio(1);                                               \
    _Pragma("unroll")                                                            \
    for (int ks = 0; ks < 4; ++ks) {                                             \
        _Pragma("unroll")                                                        \
        for (int mm = 0; mm < 2; ++mm) {                                         \
            acc[(MB) + mm][NB] = __builtin_amdgcn_mfma_f32_32x32x16_bf16(        \
                af[mm][ks], bfr[NB][ks], acc[(MB) + mm][NB], 0, 0, 0);           \
        }                                                                        \
    }                                                                            \
    __builtin_amdgcn_s_setprio(0)

template <bool SPLIT>
__global__ __launch_bounds__(512, 2)
void conv_gemm8(const bf16* __restrict__ Wbase, const bf16* __restrict__ Xbase,
                bf16* __restrict__ O0, bf16* __restrict__ O1,
                long wStride, long xStride, long oStride) {
    __shared__ __align__(16) char lds[147456];

    // bijective XCD swizzle (gridDim.x % 8 == 0)
    int wg = blockIdx.x;
    int nchunk = gridDim.x >> 3;
    int swz = (wg & 7) * nchunk + (wg >> 3);
    int kp, r;
    if (SPLIT) { kp = swz & 1; r = swz >> 1; } else { kp = 0; r = swz; }
    int nt = r & 7;             // S/256
    int mt = (r >> 3) & 3;      // F/256
    int z  = r >> 5;            // j*4 + b
    int j = z >> 2, b = z & 3;
    const int kb0 = kp * 8;
    const int kbN = SPLIT ? 8 : 16;
    const int NTp = kbN * 7;

    const bf16* Wbr = Wbase + (size_t)j * wStride;                        // [7][F][F]
    const bf16* Xbr = Xbase + (size_t)j * xStride + (size_t)b * SP_ * F_; // [SP][F]
    bf16* out = (kp ? O1 : O0) + (size_t)j * oStride + (size_t)b * F_ * S_;
    const int m0 = mt * 256, n0 = nt * 256;

    const int tid = threadIdx.x;
    const int lane = tid & 63, wid = tid >> 6;
    const int wm = wid >> 2, wn = wid & 3;      // wave tile: rows wm*128, cols wn*64

    // ---- staging decode: linear LDS byte -> source element offset (inverse swizzle)
    const int tid16 = tid * 16;
    const int p0 = tid16, p1 = 8192 + tid16;
    const int lp0 = p0 ^ (((p0 >> 9) & 1) << 5);
    const int lp1 = p1 ^ (((p1 >> 9) & 1) << 5);
    const int stgO0 = (((lp0 >> 11) << 4) + ((lp0 >> 6) & 15)) * F_
                    + (((lp0 >> 10) & 1) << 5) + ((lp0 & 63) >> 1);
    const int stgO1 = (((lp1 >> 11) << 4) + ((lp1 >> 6) & 15)) * F_
                    + (((lp1 >> 10) & 1) << 5) + ((lp1 & 63) >> 1);
    // B piece decode: piece pc covers 64 rows; src elem = bsrc + pc*64*F
    const int bsrc = (((tid16 >> 11) << 4) + ((lp0 >> 6) & 15)) * F_
                   + (((lp0 >> 10) & 1) << 5) + ((lp0 & 63) >> 1);

    // ---- ds_read addressing for 32x32x16 fragments
    // LDS region layout (from staging): [subtile(16 rows)=2048B][khalf(bit10)][row(bits6-9)][64B col]
    // element (R, k): byte = (R>>4)<<11 | (k>=32)<<10 | (R&15)<<6 | ((k&31)*2 ^ ((R>>3)&1)<<5)
    const int l31 = lane & 31, l15 = lane & 15, lnH = lane >> 5;
    const int xorA = ((l31 >> 3) & 1) << 5;                 // bit3 of A row (= bit3 of l31)
    const int aBase2 = wm * 16384 + ((l31 >> 4) << 11) + (l15 << 6);
    int colKsA[4];                                          // khalf*1024 + (colbyte ^ xorA)
#pragma unroll
    for (int ks = 0; ks < 4; ++ks)
        colKsA[ks] = ((ks >> 1) << 10) + ((((ks & 1) << 5) + (lnH << 4)) ^ xorA);
    int colB0[4];
#pragma unroll
    for (int ks = 0; ks < 4; ++ks)
        colB0[ks] = ((ks >> 1) << 10) + (((ks & 1) << 5) + (lnH << 4));
    int bRow[7], bXor[7];
#pragma unroll
    for (int t = 0; t < 7; ++t) {
        int R = wn * 64 + l31 + t;                          // shifted B row (tap t)
        bRow[t] = ((R >> 4) << 11) + ((R & 15) << 6);
        bXor[t] = ((R >> 3) & 1) << 5;
    }

    f32x16 acc[4][2] = {};    // [mt2][nt2], 32x32 tiles
    s16x8 af[2][4], bfr[2][4];

    auto STGA = [&](int regionByte, const bf16* src) {   // 16KB region, 2 loads
        async16(src + stgO0, lds + regionByte + tid16);
        async16(src + stgO1, lds + regionByte + 8192 + tid16);
    };
    auto STGB = [&](int kb1, int pc) {                   // 8KB piece, 1 load
        const bf16* src = Xbr + (size_t)n0 * F_ + kb1 * 64 + bsrc + pc * 64 * F_;
        async16(src, lds + 65536 + (kb1 & 1) * 40960 + pc * 8192 + tid16);
    };
    auto ASRC = [&](int kb, int t, int h) {
        return Wbr + (size_t)t * FF_ + (size_t)(m0 + h * 128) * F_ + kb * 64;
    };

    // ---- prologue: B(kb0) whole, A(kt0) both halves, A0(kt1). keep-2 = A0(kt1)
    STGB(kb0, 0); STGB(kb0, 1); STGB(kb0, 2); STGB(kb0, 3); STGB(kb0, 4);
    STGA(0,     ASRC(kb0, 0, 0));     // A0(kt0) bufA0
    STGA(16384, ASRC(kb0, 0, 1));     // A1(kt0) bufA0
    STGA(32768, ASRC(kb0, 1, 0));     // A0(kt1) bufA1
    asm volatile("s_waitcnt vmcnt(2)" ::: "memory");
    BARRIER();

    for (int kb = kb0; kb < kb0 + kbN; ++kb) {
        const int bB = 65536 + (kb & 1) * 40960;
#pragma unroll
        for (int t = 0; t < 7; ++t) {
            const int ktl = (kb - kb0) * 7 + t;
            const int pA = (kb + t) & 1;                 // (kb*7+t)&1
            const char* la = lds + pA * 32768 + aBase2;
            const char* lbt = lds + bB + bRow[t];
            const int bx = bXor[t];
            const int t1 = (t == 6) ? 0 : t + 1;         // kt+1 decomposition
            const int kb1 = (t == 6) ? kb + 1 : kb;
            const int t2 = (t >= 5) ? t - 5 : t + 2;     // kt+2 decomposition
            const int kb2 = (t >= 5) ? kb + 1 : kb;
            const bool bstage = (t >= 1 && t <= 5) && (kb - kb0) < kbN - 1;

            // ---- phase 1: read A rows 0-63 (mt2 0,1) + B nt2=0; stage A1(kt+1)
#pragma unroll
            for (int mm = 0; mm < 2; ++mm)
#pragma unroll
                for (int ks = 0; ks < 4; ++ks)
                    af[mm][ks] = *(const s16x8*)(la + mm * 4096 + colKsA[ks]);
#pragma unroll
            for (int ks = 0; ks < 4; ++ks)
                bfr[0][ks] = *(const s16x8*)(lbt + (colB0[ks] ^ bx));
            if (ktl + 1 < NTp) STGA((pA ^ 1) * 32768 + 16384, ASRC(kb1, t1, 1));
            BARRIER();
            MFMA_OCT(0, 0);
            BARRIER();

            // ---- phase 2: read B nt2=1; stage one B(kb+1) piece (t=1..5)
#pragma unroll
            for (int ks = 0; ks < 4; ++ks)
                bfr[1][ks] = *(const s16x8*)(lbt + 4096 + (colB0[ks] ^ bx));
            if (bstage) STGB(kb + 1, t - 1);
            BARRIER();
            MFMA_OCT(0, 1);
            BARRIER();

            // ---- phase 3: read A rows 64-127 (mt2 2,3)
#pragma unroll
            for (int mm = 0; mm < 2; ++mm)
#pragma unroll
                for (int ks = 0; ks < 4; ++ks)
                    af[mm][ks] = *(const s16x8*)(la + (2 + mm) * 4096 + colKsA[ks]);
            BARRIER();
            MFMA_OCT(2, 0);
            BARRIER();

            // ---- phase 4: stage A0(kt+2) into this A-buf; MFMA; counted vmcnt
            if (ktl + 2 < NTp) STGA(pA * 32768, ASRC(kb2, t2, 0));
            MFMA_OCT(2, 1);
            if (ktl < NTp - 2) {
                if (bstage) { asm volatile("s_waitcnt vmcnt(3)" ::: "memory"); }
                else        { asm volatile("s_waitcnt vmcnt(2)" ::: "memory"); }
            } else {
                asm volatile("s_waitcnt vmcnt(0)" ::: "memory");
            }
            BARRIER();
        }
    }

    // epilogue: 32x32 C/D layout col=lane&31, row=(reg&3)+8*(reg>>2)+4*(lane>>5)
#pragma unroll
    for (int mt2 = 0; mt2 < 4; ++mt2)
#pragma unroll
        for (int nt2 = 0; nt2 < 2; ++nt2)
#pragma unroll
            for (int rg = 0; rg < 16; ++rg) {
                int rr = m0 + wm * 128 + mt2 * 32 + (rg & 3) + ((rg >> 2) << 3) + (lnH << 2);
                int cc = n0 + wn * 64 + nt2 * 32 + l31;
                out[(size_t)rr * S_ + cc] = __float2bfloat16(acc[mt2][nt2][rg]);
            }
}

// d += a (bf16, row-wise), AND compute relu row-stats of the sum in one pass.
__global__ void addb_stats(const bf16* __restrict__ a, bf16* __restrict__ d,
                           float2* __restrict__ stats) {
    int row = blockIdx.x * 4 + (threadIdx.x >> 6);
    int lane = threadIdx.x & 63;
    const s16x8* pa = (const s16x8*)(a + (size_t)row * S_);
    s16x8* pd = (s16x8*)(d + (size_t)row * S_);
    float s1 = 0.f, s2 = 0.f;
#pragma unroll
    for (int q = 0; q < S_ / 512; ++q) {
        s16x8 va = pa[q * 64 + lane];
        s16x8 vd = pd[q * 64 + lane];
        s16x8 o;
#pragma unroll
        for (int e = 0; e < 8; ++e) {
            float f = bf2f((unsigned short)va[e]) + bf2f((unsigned short)vd[e]);
            bf16 h = __float2bfloat16(f);
            o[e] = (short)__bfloat16_as_ushort(h);
            float rr = fmaxf(__bfloat162float(h), 0.f);
            s1 += rr; s2 += rr * rr;
        }
        pd[q * 64 + lane] = o;
    }
#pragma unroll
    for (int dd = 32; dd; dd >>= 1) { s1 += __shfl_xor(s1, dd); s2 += __shfl_xor(s2, dd); }
    if (lane == 0) {
        float m = s1 / (float)S_;
        float ss = fmaxf(s2 - (float)S_ * m * m, 0.f);
        float denom = (sqrtf(ss) + 1e-5f) * (1.0f / sqrtf((float)S_));
        stats[row] = make_float2(m, 1.0f / denom);
    }
}

// ---------------- fallback 128x128 2-phase GEMM (small-ws path) -------------
__global__ void conv_gemm_small(const bf16* __restrict__ W7, const bf16* __restrict__ xT,
                                bf16* __restrict__ out) {
    __shared__ bf16 tA[128][64];
    __shared__ bf16 tB[128][64];
    int wg = blockIdx.x;
    int cpx = gridDim.x >> 3;
    int swz = (wg & 7) * cpx + (wg >> 3);
    int sx = swz & 15;
    int t1 = swz >> 4;
    int sy = t1 & 7;
    int b = t1 >> 3;
    const bf16* Xbr = xT + (size_t)b * SP_ * F_;
    bf16* ob = out + (size_t)b * F_ * S_;
    int m0 = sy * 128, n0 = sx * 128;
    int tid = threadIdx.x;
    int lane = tid & 63, wid = tid >> 6;
    int wm = wid >> 1, wn = wid & 1;
    f32x4 acc[4][4] = {};
    int srow = tid >> 3, cpart = tid & 7;
    for (int t = 0; t < K_; ++t) {
        const bf16* Wt = W7 + (size_t)t * FF_ + (size_t)m0 * F_;
        const bf16* Xt = Xbr + (size_t)(n0 + t) * F_;
        for (int kb = 0; kb < F_ / 64; ++kb) {
            const bf16* wa = Wt + kb * 64 + cpart * 8;
            const bf16* xa = Xt + kb * 64 + cpart * 8;
#pragma unroll
            for (int q = 0; q < 4; ++q) async16(wa + (size_t)(q * 32 + srow) * F_, &tA[q * 32 + srow][cpart * 8]);
#pragma unroll
            for (int q = 0; q < 4; ++q) async16(xa + (size_t)(q * 32 + srow) * F_, &tB[q * 32 + srow][cpart * 8]);
            __syncthreads();
#pragma unroll
            for (int kk = 0; kk < 2; ++kk) {
                int krow = kk * 32 + (lane >> 4) * 8;
                s16x8 a2[4], b2[4];
#pragma unroll
                for (int m = 0; m < 4; ++m) a2[m] = *(const s16x8*)&tA[wm * 64 + m * 16 + (lane & 15)][krow];
#pragma unroll
                for (int n = 0; n < 4; ++n) b2[n] = *(const s16x8*)&tB[wn * 64 + n * 16 + (lane & 15)][krow];
#pragma unroll
                for (int m = 0; m < 4; ++m)
#pragma unroll
                    for (int n = 0; n < 4; ++n)
                        acc[m][n] = __builtin_amdgcn_mfma_f32_16x16x32_bf16(a2[m], b2[n], acc[m][n], 0, 0, 0);
            }
            __syncthreads();
        }
    }
    int cm = (lane >> 4) * 4, cn = lane & 15;
#pragma unroll
    for (int m = 0; m < 4; ++m)
#pragma unroll
        for (int n = 0; n < 4; ++n)
#pragma unroll
            for (int r = 0; r < 4; ++r)
                ob[(size_t)(m0 + wm * 64 + m * 16 + cm + r) * S_ + n0 + wn * 64 + n * 16 + cn] =
                    __float2bfloat16(acc[m][n][r]);
}

// ---------------------------------------------------------------------------
__global__ void rowstats_bf16(const bf16* __restrict__ x, float2* __restrict__ stats) {
    int row = blockIdx.x * 4 + (threadIdx.x >> 6);
    int lane = threadIdx.x & 63;
    const bf16* p = x + (size_t)row * S_;
    float s1 = 0.f, s2 = 0.f;
#pragma unroll
    for (int q = 0; q < S_ / 512; ++q) {
        s16x8 v = *(const s16x8*)(p + q * 512 + lane * 8);
#pragma unroll
        for (int e = 0; e < 8; ++e) {
            float f = fmaxf(bf2f((unsigned short)v[e]), 0.f);
            s1 += f; s2 += f * f;
        }
    }
#pragma unroll
    for (int d = 32; d; d >>= 1) { s1 += __shfl_xor(s1, d); s2 += __shfl_xor(s2, d); }
    if (lane == 0) {
        float m = s1 / (float)S_;
        float ss = fmaxf(s2 - (float)S_ * m * m, 0.f);
        float denom = (sqrtf(ss) + 1e-5f) * (1.0f / sqrtf((float)S_));
        stats[row] = make_float2(m, 1.0f / denom);
    }
}

__global__ void rowstats_f32(const float* __restrict__ x, float2* __restrict__ stats) {
    int row = blockIdx.x * 4 + (threadIdx.x >> 6);
    int lane = threadIdx.x & 63;
    const float* p = x + (size_t)row * S_;
    float s1 = 0.f, s2 = 0.f;
#pragma unroll
    for (int q = 0; q < S_; q += 256) {
        float4 v = *(const float4*)(p + q + lane * 4);
        float a = fmaxf(v.x, 0.f), bb = fmaxf(v.y, 0.f);
        float c = fmaxf(v.z, 0.f), d = fmaxf(v.w, 0.f);
        s1 += a + bb + c + d;
        s2 += a * a + bb * bb + c * c + d * d;
    }
#pragma unroll
    for (int d = 32; d; d >>= 1) { s1 += __shfl_xor(s1, d); s2 += __shfl_xor(s2, d); }
    if (lane == 0) {
        float m = s1 / (float)S_;
        float ss = fmaxf(s2 - (float)S_ * m * m, 0.f);
        float denom = (sqrtf(ss) + 1e-5f) * (1.0f / sqrtf((float)S_));
        stats[row] = make_float2(m, 1.0f / denom);
    }
}

__global__ void normT(const bf16* __restrict__ x, const float2* __restrict__ stats,
                      bf16* __restrict__ hT) {
    __shared__ bf16 tile[64][72];
    int z = blockIdx.z;
    int f0 = blockIdx.y * 64, s0 = blockIdx.x * 64;
    const bf16* xb = x + (size_t)z * F_ * S_;
    bf16* hb = hT + (size_t)z * SP_ * F_;
    const float2* st = stats + (size_t)z * F_;
    int i = threadIdx.x >> 3;
    int c8 = threadIdx.x & 7;
#pragma unroll
    for (int p = 0; p < 2; ++p) {
        int r = i + p * 32;
        float2 s = st[f0 + r];
        s16x8 v = *(const s16x8*)(xb + (size_t)(f0 + r) * S_ + s0 + c8 * 8);
#pragma unroll
        for (int e = 0; e < 8; ++e) {
            float f = fmaxf(bf2f((unsigned short)v[e]), 0.f);
            tile[r][c8 * 8 + e] = __float2bfloat16((f - s.x) * s.y);
        }
    }
    __syncthreads();
    int tj = threadIdx.x & 63;
    int t4 = threadIdx.x >> 6;
#pragma unroll
    for (int r = 0; r < 16; ++r) {
        int jrow = r * 4 + t4;
        hb[(size_t)(6 + s0 + jrow) * F_ + f0 + tj] = tile[tj][jrow];
    }
}

// ---- cumsum/combine: plain (fallback) and split-K fused (2-buffer) variants
__global__ void combine_partial(const bf16* __restrict__ depth,
                                float* __restrict__ partials) {
    int idx = blockIdx.x * 256 + threadIdx.x;
    int s = idx & (S_ - 1);
    int t = idx / S_;
    int fc = t % NC_;
    int b = t / NC_;
    const bf16* p = depth + (size_t)b * F_ * S_ + (size_t)(fc * FC_) * S_ + s;
    float acc = 0.f;
#pragma unroll
    for (int f = 0; f < FC_; ++f) acc += __bfloat162float(p[(size_t)f * S_]);
    partials[idx] = acc;
}

__global__ void combine_partial2(const bf16* __restrict__ dA, const bf16* __restrict__ dB,
                                 float* __restrict__ partials) {
    int idx = blockIdx.x * 256 + threadIdx.x;
    int s = idx & (S_ - 1);
    int t = idx / S_;
    int fc = t % NC_;
    int b = t / NC_;
    size_t base = (size_t)b * F_ * S_ + (size_t)(fc * FC_) * S_ + s;
    float acc = 0.f;
#pragma unroll
    for (int f = 0; f < FC_; ++f) {
        size_t o = base + (size_t)f * S_;
        acc += __bfloat162float(dA[o]) + __bfloat162float(dB[o]);
    }
    partials[idx] = acc;
}

__global__ void combine_apply(const float* __restrict__ inp, const float* __restrict__ divisor,
                              const bf16* __restrict__ depth, const bf16* __restrict__ point,
                              const bf16* __restrict__ shiftb,
                              const float* __restrict__ partials, float* __restrict__ y) {
    int idx = blockIdx.x * 256 + threadIdx.x;
    int s = idx & (S_ - 1);
    int t = idx / S_;
    int fc = t % NC_;
    int b = t / NC_;
    float acc = 0.f;
    const float* pp = partials + (size_t)b * NC_ * S_ + s;
    for (int c = 0; c < fc; ++c) acc += pp[(size_t)c * S_];
    size_t base = (size_t)b * F_ * S_ + (size_t)(fc * FC_) * S_ + s;
#pragma unroll 4
    for (int f = 0; f < FC_; ++f) {
        size_t o = base + (size_t)f * S_;
        acc += __bfloat162float(depth[o]);
        float yv = inp[o] * (acc / divisor[fc * FC_ + f] + __bfloat162float(point[o]))
                 + __bfloat162float(shiftb[o]);
        y[o] = yv;
    }
}

// split-K fused: branches live as two halves h0[3][B][F][S] + h1[...]; y is bf16
__global__ void combine_apply2(const float* __restrict__ inp, const float* __restrict__ divisor,
                               const bf16* __restrict__ h0, const bf16* __restrict__ h1,
                               const float* __restrict__ partials, bf16* __restrict__ y) {
    int idx = blockIdx.x * 256 + threadIdx.x;
    int s = idx & (S_ - 1);
    int t = idx / S_;
    int fc = t % NC_;
    int b = t / NC_;
    float acc = 0.f;
    const float* pp = partials + (size_t)b * NC_ * S_ + s;
    for (int c = 0; c < fc; ++c) acc += pp[(size_t)c * S_];
    size_t base = (size_t)b * F_ * S_ + (size_t)(fc * FC_) * S_ + s;
#pragma unroll 4
    for (int f = 0; f < FC_; ++f) {
        size_t o = base + (size_t)f * S_;
        float dep = __bfloat162float(h0[o]) + __bfloat162float(h1[o]);
        float poi = __bfloat162float(h0[o + BFS_]) + __bfloat162float(h1[o + BFS_]);
        float shi = __bfloat162float(h0[o + 2 * BFS_]) + __bfloat162float(h1[o + 2 * BFS_]);
        acc += dep;
        float yv = inp[o] * (acc / divisor[fc * FC_ + f] + poi) + shi;
        y[o] = __float2bfloat16(yv);
    }
}

__global__ void finalnorm(const float* __restrict__ y, const float2* __restrict__ stats,
                          float* __restrict__ out) {
    size_t i = (size_t)blockIdx.x * 256 + threadIdx.x;
    if (i >= (size_t)B_ * F_ * S_) return;
    float2 st = stats[i / S_];
    float v = fmaxf(y[i], 0.f);
    out[i] = (v - st.x) * st.y;
}

// bf16-y variant, 8 elems/thread
__global__ void finalnorm_bf(const bf16* __restrict__ y, const float2* __restrict__ stats,
                             float* __restrict__ out) {
    size_t i8 = (size_t)blockIdx.x * 256 + threadIdx.x;   // over BFS/8
    size_t row = i8 >> 8;                                  // S/8 = 256 chunks per row
    float2 st = stats[row];
    s16x8 v = ((const s16x8*)y)[i8];
    float* o = out + i8 * 8;
#pragma unroll
    for (int e = 0; e < 8; ++e) {
        float f = fmaxf(bf2f((unsigned short)v[e]), 0.f);
        o[e] = (f - st.x) * st.y;
    }
}

// ---------------------------------------------------------------------------
extern "C" void kernel_launch(void* const* d_in, const int* in_sizes, int n_in,
                              void* d_out, int out_size, void* d_ws, size_t ws_size,
                              hipStream_t stream) {
    const float* inp = (const float*)d_in[0];
    const float* pos = (const float*)d_in[1];
    const float* divisor = (const float*)d_in[2];
    const float* w[6] = { (const float*)d_in[3], (const float*)d_in[4],
                          (const float*)d_in[5], (const float*)d_in[6],
                          (const float*)d_in[7], (const float*)d_in[8] };
    float* out = (float*)d_out;

    size_t off = 0;
    auto alloc = [&](size_t bytes) {
        off = (off + 255) & ~(size_t)255;
        void* r = (char*)d_ws + off;
        off += bytes;
        return r;
    };

    const size_t needB = ((BSPF_ * 2 + 255) & ~255UL)
                       + ((3 * BSPF_ * 2 + 255) & ~255UL)
                       + ((3 * 7 * FF_ * 2 + 255) & ~255UL)
                       + ((3 * BFS_ * 2 + 255) & ~255UL)
                       + ((3 * BFS_ * 2 + 255) & ~255UL)
                       + ((3 * B_ * F_ * 8 + 255) & ~255UL)
                       + ((B_ * NC_ * S_ * 4 + 255) & ~255UL)
                       + 4096;
    const size_t needC = needB + ((3 * BFS_ * 2 + 255) & ~255UL);   // + split-K partials

    if (ws_size >= needB) {
        const bool splitK = (ws_size >= needC);
        // NOTE: allocation ORDER matters — conv_gemm8's B staging overreads up
        // to 58 rows past a slab end (never consumed); xT overflow lands in
        // hT3, hT3 overflow lands in Wb3. Keep xT -> hT3 -> Wb3 adjacency.
        bf16* xT   = (bf16*)alloc(BSPF_ * 2);
        bf16* hT3  = (bf16*)alloc(3 * BSPF_ * 2);
        bf16* Wb3  = (bf16*)alloc(3 * 7 * FF_ * 2);
        bf16* O3   = (bf16*)alloc(3 * BFS_ * 2);
        bf16* br3  = (bf16*)alloc(3 * BFS_ * 2);
        float2* stats3 = (float2*)alloc(3 * B_ * F_ * 8);
        float* partials = (float*)alloc(B_ * NC_ * S_ * 4);
        bf16* P0 = splitK ? (bf16*)alloc(3 * BFS_ * 2) : nullptr;

        zero_pads<<<(4 * B_ * (K_ - 1) * F_ + 255) / 256, 256, 0, stream>>>(xT, hT3, 3);
        prep_x<<<dim3(S_ / 64, F_ / 64, B_), 256, 0, stream>>>(inp, pos, xT);

        wconv3<<<dim3(F_ * F_ / 256, 3), 256, 0, stream>>>(w[0], w[2], w[4], Wb3);
        if (splitK) {
            conv_gemm8<true><<<768, 512, 0, stream>>>(Wb3, xT, P0, O3, 7 * FF_, 0, BFS_);
            addb_stats<<<3 * B_ * F_ / 4, 256, 0, stream>>>(P0, O3, stats3);
        } else {
            conv_gemm8<false><<<384, 512, 0, stream>>>(Wb3, xT, O3, O3, 7 * FF_, 0, BFS_);
            rowstats_bf16<<<3 * B_ * F_ / 4, 256, 0, stream>>>(O3, stats3);
        }
        normT<<<dim3(S_ / 64, F_ / 64, 12), 256, 0, stream>>>(O3, stats3, hT3);

        wconv3<<<dim3(F_ * F_ / 256, 3), 256, 0, stream>>>(w[1], w[3], w[5], Wb3);
        if (splitK) {
            conv_gemm8<true><<<768, 512, 0, stream>>>(Wb3, hT3, P0, br3, 7 * FF_, BSPF_, BFS_);
            bf16* ybf = O3;   // O3 dead after normT
            combine_partial2<<<B_ * NC_ * S_ / 256, 256, 0, stream>>>(P0, br3, partials);
            combine_apply2<<<B_ * NC_ * S_ / 256, 256, 0, stream>>>(
                inp, divisor, P0, br3, partials, ybf);
            rowstats_bf16<<<B_ * F_ / 4, 256, 0, stream>>>(ybf, stats3);
            finalnorm_bf<<<(int)(BFS_ / 8 / 256), 256, 0, stream>>>(ybf, stats3, out);
        } else {
            conv_gemm8<false><<<384, 512, 0, stream>>>(Wb3, hT3, br3, br3, 7 * FF_, BSPF_, BFS_);
            float* ybuf = (float*)O3;
            combine_partial<<<B_ * NC_ * S_ / 256, 256, 0, stream>>>(br3, partials);
            combine_apply<<<B_ * NC_ * S_ / 256, 256, 0, stream>>>(
                inp, divisor, br3, br3 + BFS_, br3 + 2 * BFS_, partials, ybuf);
            rowstats_f32<<<B_ * F_ / 4, 256, 0, stream>>>(ybuf, stats3);
            finalnorm<<<(B_ * F_ * S_) / 256, 256, 0, stream>>>(ybuf, stats3, out);
        }
    } else {
        // sequential fallback (compact ws), proven path
        bf16* xT   = (bf16*)alloc(BSPF_ * 2);
        bf16* hT1  = (bf16*)alloc(BSPF_ * 2);
        bf16* Wb1  = (bf16*)alloc(7 * FF_ * 2);
        bf16* O1   = (bf16*)alloc(BFS_ * 2);
        bf16* br3  = (bf16*)alloc(3 * BFS_ * 2);
        float2* stats3 = (float2*)alloc(B_ * F_ * 8);
        float* partials = (float*)alloc(B_ * NC_ * S_ * 4);
        float* ybuf = (float*)xT;

        zero_pads<<<(2 * B_ * (K_ - 1) * F_ + 255) / 256, 256, 0, stream>>>(xT, hT1, 1);
        prep_x<<<dim3(S_ / 64, F_ / 64, B_), 256, 0, stream>>>(inp, pos, xT);

        for (int j = 0; j < 3; ++j) {
            wconv<<<F_ * F_ / 256, 256, 0, stream>>>(w[2 * j], Wb1);
            conv_gemm_small<<<16 * 8 * 4, 256, 0, stream>>>(Wb1, xT, O1);
            rowstats_bf16<<<B_ * F_ / 4, 256, 0, stream>>>(O1, stats3);
            normT<<<dim3(S_ / 64, F_ / 64, 4), 256, 0, stream>>>(O1, stats3, hT1);
            wconv<<<F_ * F_ / 256, 256, 0, stream>>>(w[2 * j + 1], Wb1);
            conv_gemm_small<<<16 * 8 * 4, 256, 0, stream>>>(Wb1, hT1, br3 + j * BFS_);
        }
        combine_partial<<<B_ * NC_ * S_ / 256, 256, 0, stream>>>(br3, partials);
        combine_apply<<<B_ * NC_ * S_ / 256, 256, 0, stream>>>(
            inp, divisor, br3, br3 + BFS_, br3 + 2 * BFS_, partials, ybuf);
        rowstats_f32<<<B_ * F_ / 4, 256, 0, stream>>>(ybuf, stats3);
        finalnorm<<<(B_ * F_ * S_) / 256, 256, 0, stream>>>(ybuf, stats3, out);
    }
}

// Round 10
// 682.726 us; speedup vs baseline: 1.1092x; 1.1092x over previous
//
#include <hip/hip_runtime.h>
#include <hip/hip_bf16.h>
#include <stdint.h>

#define B_ 4
#define F_ 1024
#define S_ 2048
#define K_ 7
#define SP_ (S_ + K_ - 1)   // 2054 padded rows (6 zero rows at the front)
#define FC_ 64              // cumsum chunk size
#define NC_ (F_ / FC_)      // 16 chunks
#define FF_ ((size_t)F_ * F_)
#define BFS_ ((size_t)B_ * F_ * S_)
#define BSPF_ ((size_t)B_ * SP_ * F_)

using f32x4 = __attribute__((ext_vector_type(4))) float;
using s16x8 = __attribute__((ext_vector_type(8))) short;
using bf16 = __hip_bfloat16;

// -------- async global->LDS 16B (wave-uniform base + lane*16 semantics) -----
typedef const __attribute__((address_space(1))) void gvoid_t;
typedef __attribute__((address_space(3))) void lvoid_t;
__device__ __forceinline__ void async16(const void* g, void* l) {
    __builtin_amdgcn_global_load_lds((gvoid_t*)g, (lvoid_t*)l, 16, 0, 0);
}

__device__ __forceinline__ float bf2f(unsigned short u) {
    union { unsigned int i; float f; } c; c.i = ((unsigned int)u) << 16; return c.f;
}

#define FENCE() asm volatile("" ::: "memory")
#define BARRIER() do { FENCE(); __builtin_amdgcn_s_barrier(); FENCE(); } while (0)

// ---------------------------------------------------------------------------
__global__ void zero_pads(bf16* xT, bf16* hT, int nh) {
    int i = blockIdx.x * 256 + threadIdx.x;
    const int per = B_ * (K_ - 1) * F_;
    int total = (1 + nh) * per;
    if (i >= total) return;
    int r = i / per, o = i % per;
    int b = o / ((K_ - 1) * F_);
    int rr = o % ((K_ - 1) * F_);
    bf16 z = __float2bfloat16(0.0f);
    if (r == 0) xT[(size_t)b * SP_ * F_ + rr] = z;
    else        hT[(size_t)(r - 1) * BSPF_ + (size_t)b * SP_ * F_ + rr] = z;
}

// out = inp + pos_embd transposed to xT; optionally also emit bf16 copy of inp
__global__ void prep_x(const float* __restrict__ inp, const float* __restrict__ pos,
                       bf16* __restrict__ xT, bf16* __restrict__ inpb) {
    __shared__ bf16 tile[64][66];
    int b = blockIdx.z;
    int f0 = blockIdx.y * 64, s0 = blockIdx.x * 64;
    int tj = threadIdx.x & 63;
    int t4 = threadIdx.x >> 6;
#pragma unroll
    for (int r = 0; r < 16; ++r) {
        int i = r * 4 + t4;
        size_t off = (size_t)(f0 + i) * S_ + s0 + tj;
        float vi = inp[(size_t)b * F_ * S_ + off];
        if (inpb) inpb[(size_t)b * F_ * S_ + off] = __float2bfloat16(vi);
        tile[i][tj] = __float2bfloat16(vi + pos[off]);
    }
    __syncthreads();
#pragma unroll
    for (int r = 0; r < 16; ++r) {
        int j = r * 4 + t4;
        xT[(size_t)b * SP_ * F_ + (size_t)(6 + s0 + j) * F_ + f0 + tj] = tile[tj][j];
    }
}

// single-weight repack (sequential fallback)
__global__ void wconv(const float* __restrict__ w, bf16* __restrict__ wt) {
    int i = blockIdx.x * 256 + threadIdx.x;
    if (i >= F_ * F_) return;
    const float* src = w + (size_t)i * K_;
#pragma unroll
    for (int t = 0; t < K_; ++t)
        wt[(size_t)t * FF_ + i] = __float2bfloat16(src[t]);
}

// batched 3-weight repack: grid (FF/256, 3)
__global__ void wconv3(const float* __restrict__ w0, const float* __restrict__ w1,
                       const float* __restrict__ w2, bf16* __restrict__ wt) {
    int i = blockIdx.x * 256 + threadIdx.x;
    int z = blockIdx.y;
    const float* w = (z == 0) ? w0 : (z == 1 ? w1 : w2);
    bf16* dst = wt + (size_t)z * 7 * FF_;
    const float* src = w + (size_t)i * K_;
#pragma unroll
    for (int t = 0; t < K_; ++t)
        dst[(size_t)t * FF_ + i] = __float2bfloat16(src[t]);
}

// ---------------------------------------------------------------------------
// 256x256 bf16 conv-GEMM, BK=64, 8-phase schedule, kb-major K-order with
// SHARED B-panel across the 7 taps (tap = shifted LDS read). LDS 144 KiB.
// PROVEN at 297.9 us / 54-55% MfmaUtil (R6/R7) — byte-identical revert.
// (R8 lesson: 32x32x16 MFMA here gives only 2 independent acc chains/phase,
// 4-deep dependent — stalls the matrix pipe; 16x16x32 keeps 8 indep chains.)
#define MFMA_QUAD(MB, NB)                                                        \
    __builtin_amdgcn_s_setprio(1);                                               \
    _Pragma("unroll")                                                            \
    for (int kk = 0; kk < 2; ++kk) {                                             \
        _Pragma("unroll")                                                        \
        for (int m = 0; m < 4; ++m) {                                            \
            _Pragma("unroll")                                                    \
            for (int n = 0; n < 2; ++n) {                                        \
                acc[(MB) + m][(NB) + n] = __builtin_amdgcn_mfma_f32_16x16x32_bf16( \
                    af[m][kk], bfr[(NB) + n][kk], acc[(MB) + m][(NB) + n], 0, 0, 0); \
            }                                                                    \
        }                                                                        \
    }                                                                            \
    __builtin_amdgcn_s_setprio(0)

template <bool SPLIT>
__global__ __launch_bounds__(512, 2)
void conv_gemm8(const bf16* __restrict__ Wbase, const bf16* __restrict__ Xbase,
                bf16* __restrict__ O0, bf16* __restrict__ O1,
                long wStride, long xStride, long oStride) {
    __shared__ __align__(16) char lds[147456];

    // bijective XCD swizzle (gridDim.x % 8 == 0)
    int wg = blockIdx.x;
    int nchunk = gridDim.x >> 3;
    int swz = (wg & 7) * nchunk + (wg >> 3);
    int kp, r;
    if (SPLIT) { kp = swz & 1; r = swz >> 1; } else { kp = 0; r = swz; }
    int nt = r & 7;             // S/256
    int mt = (r >> 3) & 3;      // F/256
    int z  = r >> 5;            // j*4 + b
    int j = z >> 2, b = z & 3;
    const int kb0 = kp * 8;
    const int kbN = SPLIT ? 8 : 16;
    const int NTp = kbN * 7;

    const bf16* Wbr = Wbase + (size_t)j * wStride;                        // [7][F][F]
    const bf16* Xbr = Xbase + (size_t)j * xStride + (size_t)b * SP_ * F_; // [SP][F]
    bf16* out = (kp ? O1 : O0) + (size_t)j * oStride + (size_t)b * F_ * S_;
    const int m0 = mt * 256, n0 = nt * 256;

    const int tid = threadIdx.x;
    const int lane = tid & 63, wid = tid >> 6;
    const int wm = wid >> 2, wn = wid & 3;      // wave tile: rows wm*128, cols wn*64

    // ---- staging decode: linear LDS byte -> source element offset (inverse swizzle)
    const int tid16 = tid * 16;
    const int p0 = tid16, p1 = 8192 + tid16;
    const int lp0 = p0 ^ (((p0 >> 9) & 1) << 5);
    const int lp1 = p1 ^ (((p1 >> 9) & 1) << 5);
    const int stgO0 = (((lp0 >> 11) << 4) + ((lp0 >> 6) & 15)) * F_
                    + (((lp0 >> 10) & 1) << 5) + ((lp0 & 63) >> 1);
    const int stgO1 = (((lp1 >> 11) << 4) + ((lp1 >> 6) & 15)) * F_
                    + (((lp1 >> 10) & 1) << 5) + ((lp1 & 63) >> 1);
    // B piece decode: piece pc covers 64 rows; src elem = bsrc + pc*64*F
    const int bsrc = (((tid16 >> 11) << 4) + ((lp0 >> 6) & 15)) * F_
                   + (((lp0 >> 10) & 1) << 5) + ((lp0 & 63) >> 1);

    // ---- ds_read swizzled offsets
    const int rA = lane & 15, cA = (lane >> 4) * 8;
    const int swzRC = (rA << 6) + ((cA << 1) ^ (((rA >> 3) & 1) << 5));
    const int aOffBase = wm * 16384 + swzRC;
    int addrB[7];
#pragma unroll
    for (int t = 0; t < 7; ++t) {
        int R = wn * 64 + rA + t;           // shifted B row (tap t)
        addrB[t] = ((R >> 4) << 11) + ((R & 15) << 6)
                 + ((cA << 1) ^ (((R >> 3) & 1) << 5));
    }

    f32x4 acc[8][4] = {};
    s16x8 af[4][2], bfr[4][2];

    auto STGA = [&](int regionByte, const bf16* src) {   // 16KB region, 2 loads
        async16(src + stgO0, lds + regionByte + tid16);
        async16(src + stgO1, lds + regionByte + 8192 + tid16);
    };
    auto STGB = [&](int kb1, int pc) {                   // 8KB piece, 1 load
        const bf16* src = Xbr + (size_t)n0 * F_ + kb1 * 64 + bsrc + pc * 64 * F_;
        async16(src, lds + 65536 + (kb1 & 1) * 40960 + pc * 8192 + tid16);
    };
    auto ASRC = [&](int kb, int t, int h) {
        return Wbr + (size_t)t * FF_ + (size_t)(m0 + h * 128) * F_ + kb * 64;
    };

    // ---- prologue: B(kb0) whole, A(kt0) both halves, A0(kt1). keep-2 = A0(kt1)
    STGB(kb0, 0); STGB(kb0, 1); STGB(kb0, 2); STGB(kb0, 3); STGB(kb0, 4);
    STGA(0,     ASRC(kb0, 0, 0));     // A0(kt0) bufA0
    STGA(16384, ASRC(kb0, 0, 1));     // A1(kt0) bufA0
    STGA(32768, ASRC(kb0, 1, 0));     // A0(kt1) bufA1
    asm volatile("s_waitcnt vmcnt(2)" ::: "memory");
    BARRIER();

    for (int kb = kb0; kb < kb0 + kbN; ++kb) {
        const int bB = 65536 + (kb & 1) * 40960;
#pragma unroll
        for (int t = 0; t < 7; ++t) {
            const int ktl = (kb - kb0) * 7 + t;
            const int pA = (kb + t) & 1;                 // (kb*7+t)&1
            const char* la = lds + pA * 32768 + aOffBase;
            const char* lb = lds + bB + addrB[t];
            const int t1 = (t == 6) ? 0 : t + 1;         // kt+1 decomposition
            const int kb1 = (t == 6) ? kb + 1 : kb;
            const int t2 = (t >= 5) ? t - 5 : t + 2;     // kt+2 decomposition
            const int kb2 = (t >= 5) ? kb + 1 : kb;
            const bool bstage = (t >= 1 && t <= 5) && (kb - kb0) < kbN - 1;

            // ---- phase 1: read A-mh0 + B-nh0; stage A1(kt+1) into other A-buf
#pragma unroll
            for (int m = 0; m < 4; ++m) {
                af[m][0] = *(const s16x8*)(la + m * 2048);
                af[m][1] = *(const s16x8*)(la + m * 2048 + 1024);
            }
#pragma unroll
            for (int n = 0; n < 2; ++n) {
                bfr[n][0] = *(const s16x8*)(lb + n * 2048);
                bfr[n][1] = *(const s16x8*)(lb + n * 2048 + 1024);
            }
            if (ktl + 1 < NTp) STGA((pA ^ 1) * 32768 + 16384, ASRC(kb1, t1, 1));
            BARRIER();
            MFMA_QUAD(0, 0);
            BARRIER();

            // ---- phase 2: read B-nh1; stage one B(kb+1) piece (t=1..5)
#pragma unroll
            for (int n = 0; n < 2; ++n) {
                bfr[2 + n][0] = *(const s16x8*)(lb + (2 + n) * 2048);
                bfr[2 + n][1] = *(const s16x8*)(lb + (2 + n) * 2048 + 1024);
            }
            if (bstage) STGB(kb + 1, t - 1);
            BARRIER();
            MFMA_QUAD(0, 2);
            BARRIER();

            // ---- phase 3: read A-mh1
#pragma unroll
            for (int m = 0; m < 4; ++m) {
                af[m][0] = *(const s16x8*)(la + (4 + m) * 2048);
                af[m][1] = *(const s16x8*)(la + (4 + m) * 2048 + 1024);
            }
            BARRIER();
            MFMA_QUAD(4, 0);
            BARRIER();

            // ---- phase 4: stage A0(kt+2) into this A-buf; MFMA; counted vmcnt
            if (ktl + 2 < NTp) STGA(pA * 32768, ASRC(kb2, t2, 0));
            MFMA_QUAD(4, 2);
            if (ktl < NTp - 2) {
                if (bstage) { asm volatile("s_waitcnt vmcnt(3)" ::: "memory"); }
                else        { asm volatile("s_waitcnt vmcnt(2)" ::: "memory"); }
            } else {
                asm volatile("s_waitcnt vmcnt(0)" ::: "memory");
            }
            BARRIER();
        }
    }

    // epilogue: C/D layout col=lane&15, row=(lane>>4)*4+reg  [m89-verified]
    const int cm = (lane >> 4) * 4, cn = lane & 15;
#pragma unroll
    for (int mf = 0; mf < 8; ++mf)
#pragma unroll
        for (int nf = 0; nf < 4; ++nf)
#pragma unroll
            for (int r2 = 0; r2 < 4; ++r2) {
                int rr = m0 + wm * 128 + mf * 16 + cm + r2;
                int cc = n0 + wn * 64 + nf * 16 + cn;
                out[(size_t)rr * S_ + cc] = __float2bfloat16(acc[mf][nf][r2]);
            }
}

// d += a (bf16, row-wise), AND compute relu row-stats of the sum in one pass.
__global__ void addb_stats(const bf16* __restrict__ a, bf16* __restrict__ d,
                           float2* __restrict__ stats) {
    int row = blockIdx.x * 4 + (threadIdx.x >> 6);
    int lane = threadIdx.x & 63;
    const s16x8* pa = (const s16x8*)(a + (size_t)row * S_);
    s16x8* pd = (s16x8*)(d + (size_t)row * S_);
    float s1 = 0.f, s2 = 0.f;
#pragma unroll
    for (int q = 0; q < S_ / 512; ++q) {
        s16x8 va = pa[q * 64 + lane];
        s16x8 vd = pd[q * 64 + lane];
        s16x8 o;
#pragma unroll
        for (int e = 0; e < 8; ++e) {
            float f = bf2f((unsigned short)va[e]) + bf2f((unsigned short)vd[e]);
            bf16 h = __float2bfloat16(f);
            o[e] = (short)__bfloat16_as_ushort(h);
            float rr = fmaxf(__bfloat162float(h), 0.f);
            s1 += rr; s2 += rr * rr;
        }
        pd[q * 64 + lane] = o;
    }
#pragma unroll
    for (int dd = 32; dd; dd >>= 1) { s1 += __shfl_xor(s1, dd); s2 += __shfl_xor(s2, dd); }
    if (lane == 0) {
        float m = s1 / (float)S_;
        float ss = fmaxf(s2 - (float)S_ * m * m, 0.f);
        float denom = (sqrtf(ss) + 1e-5f) * (1.0f / sqrtf((float)S_));
        stats[row] = make_float2(m, 1.0f / denom);
    }
}

// ---------------- fallback 128x128 2-phase GEMM (small-ws path) -------------
__global__ void conv_gemm_small(const bf16* __restrict__ W7, const bf16* __restrict__ xT,
                                bf16* __restrict__ out) {
    __shared__ bf16 tA[128][64];
    __shared__ bf16 tB[128][64];
    int wg = blockIdx.x;
    int cpx = gridDim.x >> 3;
    int swz = (wg & 7) * cpx + (wg >> 3);
    int sx = swz & 15;
    int t1 = swz >> 4;
    int sy = t1 & 7;
    int b = t1 >> 3;
    const bf16* Xbr = xT + (size_t)b * SP_ * F_;
    bf16* ob = out + (size_t)b * F_ * S_;
    int m0 = sy * 128, n0 = sx * 128;
    int tid = threadIdx.x;
    int lane = tid & 63, wid = tid >> 6;
    int wm = wid >> 1, wn = wid & 1;
    f32x4 acc[4][4] = {};
    int srow = tid >> 3, cpart = tid & 7;
    for (int t = 0; t < K_; ++t) {
        const bf16* Wt = W7 + (size_t)t * FF_ + (size_t)m0 * F_;
        const bf16* Xt = Xbr + (size_t)(n0 + t) * F_;
        for (int kb = 0; kb < F_ / 64; ++kb) {
            const bf16* wa = Wt + kb * 64 + cpart * 8;
            const bf16* xa = Xt + kb * 64 + cpart * 8;
#pragma unroll
            for (int q = 0; q < 4; ++q) async16(wa + (size_t)(q * 32 + srow) * F_, &tA[q * 32 + srow][cpart * 8]);
#pragma unroll
            for (int q = 0; q < 4; ++q) async16(xa + (size_t)(q * 32 + srow) * F_, &tB[q * 32 + srow][cpart * 8]);
            __syncthreads();
#pragma unroll
            for (int kk = 0; kk < 2; ++kk) {
                int krow = kk * 32 + (lane >> 4) * 8;
                s16x8 a2[4], b2[4];
#pragma unroll
                for (int m = 0; m < 4; ++m) a2[m] = *(const s16x8*)&tA[wm * 64 + m * 16 + (lane & 15)][krow];
#pragma unroll
                for (int n = 0; n < 4; ++n) b2[n] = *(const s16x8*)&tB[wn * 64 + n * 16 + (lane & 15)][krow];
#pragma unroll
                for (int m = 0; m < 4; ++m)
#pragma unroll
                    for (int n = 0; n < 4; ++n)
                        acc[m][n] = __builtin_amdgcn_mfma_f32_16x16x32_bf16(a2[m], b2[n], acc[m][n], 0, 0, 0);
            }
            __syncthreads();
        }
    }
    int cm = (lane >> 4) * 4, cn = lane & 15;
#pragma unroll
    for (int m = 0; m < 4; ++m)
#pragma unroll
        for (int n = 0; n < 4; ++n)
#pragma unroll
            for (int r = 0; r < 4; ++r)
                ob[(size_t)(m0 + wm * 64 + m * 16 + cm + r) * S_ + n0 + wn * 64 + n * 16 + cn] =
                    __float2bfloat16(acc[m][n][r]);
}

// ---------------------------------------------------------------------------
__global__ void rowstats_bf16(const bf16* __restrict__ x, float2* __restrict__ stats) {
    int row = blockIdx.x * 4 + (threadIdx.x >> 6);
    int lane = threadIdx.x & 63;
    const bf16* p = x + (size_t)row * S_;
    float s1 = 0.f, s2 = 0.f;
#pragma unroll
    for (int q = 0; q < S_ / 512; ++q) {
        s16x8 v = *(const s16x8*)(p + q * 512 + lane * 8);
#pragma unroll
        for (int e = 0; e < 8; ++e) {
            float f = fmaxf(bf2f((unsigned short)v[e]), 0.f);
            s1 += f; s2 += f * f;
        }
    }
#pragma unroll
    for (int d = 32; d; d >>= 1) { s1 += __shfl_xor(s1, d); s2 += __shfl_xor(s2, d); }
    if (lane == 0) {
        float m = s1 / (float)S_;
        float ss = fmaxf(s2 - (float)S_ * m * m, 0.f);
        float denom = (sqrtf(ss) + 1e-5f) * (1.0f / sqrtf((float)S_));
        stats[row] = make_float2(m, 1.0f / denom);
    }
}

__global__ void rowstats_f32(const float* __restrict__ x, float2* __restrict__ stats) {
    int row = blockIdx.x * 4 + (threadIdx.x >> 6);
    int lane = threadIdx.x & 63;
    const float* p = x + (size_t)row * S_;
    float s1 = 0.f, s2 = 0.f;
#pragma unroll
    for (int q = 0; q < S_; q += 256) {
        float4 v = *(const float4*)(p + q + lane * 4);
        float a = fmaxf(v.x, 0.f), bb = fmaxf(v.y, 0.f);
        float c = fmaxf(v.z, 0.f), d = fmaxf(v.w, 0.f);
        s1 += a + bb + c + d;
        s2 += a * a + bb * bb + c * c + d * d;
    }
#pragma unroll
    for (int d = 32; d; d >>= 1) { s1 += __shfl_xor(s1, d); s2 += __shfl_xor(s2, d); }
    if (lane == 0) {
        float m = s1 / (float)S_;
        float ss = fmaxf(s2 - (float)S_ * m * m, 0.f);
        float denom = (sqrtf(ss) + 1e-5f) * (1.0f / sqrtf((float)S_));
        stats[row] = make_float2(m, 1.0f / denom);
    }
}

__global__ void normT(const bf16* __restrict__ x, const float2* __restrict__ stats,
                      bf16* __restrict__ hT) {
    __shared__ bf16 tile[64][72];
    int z = blockIdx.z;
    int f0 = blockIdx.y * 64, s0 = blockIdx.x * 64;
    const bf16* xb = x + (size_t)z * F_ * S_;
    bf16* hb = hT + (size_t)z * SP_ * F_;
    const float2* st = stats + (size_t)z * F_;
    int i = threadIdx.x >> 3;
    int c8 = threadIdx.x & 7;
#pragma unroll
    for (int p = 0; p < 2; ++p) {
        int r = i + p * 32;
        float2 s = st[f0 + r];
        s16x8 v = *(const s16x8*)(xb + (size_t)(f0 + r) * S_ + s0 + c8 * 8);
#pragma unroll
        for (int e = 0; e < 8; ++e) {
            float f = fmaxf(bf2f((unsigned short)v[e]), 0.f);
            tile[r][c8 * 8 + e] = __float2bfloat16((f - s.x) * s.y);
        }
    }
    __syncthreads();
    int tj = threadIdx.x & 63;
    int t4 = threadIdx.x >> 6;
#pragma unroll
    for (int r = 0; r < 16; ++r) {
        int jrow = r * 4 + t4;
        hb[(size_t)(6 + s0 + jrow) * F_ + f0 + tj] = tile[tj][jrow];
    }
}

// ---- cumsum/combine: plain (fallback) and split-K fused (2-buffer) variants
__global__ void combine_partial(const bf16* __restrict__ depth,
                                float* __restrict__ partials) {
    int idx = blockIdx.x * 256 + threadIdx.x;
    int s = idx & (S_ - 1);
    int t = idx / S_;
    int fc = t % NC_;
    int b = t / NC_;
    const bf16* p = depth + (size_t)b * F_ * S_ + (size_t)(fc * FC_) * S_ + s;
    float acc = 0.f;
#pragma unroll
    for (int f = 0; f < FC_; ++f) acc += __bfloat162float(p[(size_t)f * S_]);
    partials[idx] = acc;
}

__global__ void combine_partial2(const bf16* __restrict__ dA, const bf16* __restrict__ dB,
                                 float* __restrict__ partials) {
    int idx = blockIdx.x * 256 + threadIdx.x;
    int s = idx & (S_ - 1);
    int t = idx / S_;
    int fc = t % NC_;
    int b = t / NC_;
    size_t base = (size_t)b * F_ * S_ + (size_t)(fc * FC_) * S_ + s;
    float acc = 0.f;
#pragma unroll
    for (int f = 0; f < FC_; ++f) {
        size_t o = base + (size_t)f * S_;
        acc += __bfloat162float(dA[o]) + __bfloat162float(dB[o]);
    }
    partials[idx] = acc;
}

__global__ void combine_apply(const float* __restrict__ inp, const float* __restrict__ divisor,
                              const bf16* __restrict__ depth, const bf16* __restrict__ point,
                              const bf16* __restrict__ shiftb,
                              const float* __restrict__ partials, float* __restrict__ y) {
    int idx = blockIdx.x * 256 + threadIdx.x;
    int s = idx & (S_ - 1);
    int t = idx / S_;
    int fc = t % NC_;
    int b = t / NC_;
    float acc = 0.f;
    const float* pp = partials + (size_t)b * NC_ * S_ + s;
    for (int c = 0; c < fc; ++c) acc += pp[(size_t)c * S_];
    size_t base = (size_t)b * F_ * S_ + (size_t)(fc * FC_) * S_ + s;
#pragma unroll 4
    for (int f = 0; f < FC_; ++f) {
        size_t o = base + (size_t)f * S_;
        acc += __bfloat162float(depth[o]);
        float yv = inp[o] * (acc / divisor[fc * FC_ + f] + __bfloat162float(point[o]))
                 + __bfloat162float(shiftb[o]);
        y[o] = yv;
    }
}

// split-K fused: branches as two halves h0/h1 [3][B][F][S]; inp as bf16; y bf16
__global__ void combine_apply2(const bf16* __restrict__ inpb, const float* __restrict__ divisor,
                               const bf16* __restrict__ h0, const bf16* __restrict__ h1,
                               const float* __restrict__ partials, bf16* __restrict__ y) {
    int idx = blockIdx.x * 256 + threadIdx.x;
    int s = idx & (S_ - 1);
    int t = idx / S_;
    int fc = t % NC_;
    int b = t / NC_;
    float acc = 0.f;
    const float* pp = partials + (size_t)b * NC_ * S_ + s;
    for (int c = 0; c < fc; ++c) acc += pp[(size_t)c * S_];
    size_t base = (size_t)b * F_ * S_ + (size_t)(fc * FC_) * S_ + s;
#pragma unroll 4
    for (int f = 0; f < FC_; ++f) {
        size_t o = base + (size_t)f * S_;
        float dep = __bfloat162float(h0[o]) + __bfloat162float(h1[o]);
        float poi = __bfloat162float(h0[o + BFS_]) + __bfloat162float(h1[o + BFS_]);
        float shi = __bfloat162float(h0[o + 2 * BFS_]) + __bfloat162float(h1[o + 2 * BFS_]);
        acc += dep;
        float yv = __bfloat162float(inpb[o]) * (acc / divisor[fc * FC_ + f] + poi) + shi;
        y[o] = __float2bfloat16(yv);
    }
}

// f32-inp variant (used when ws lacks room for inpb)
__global__ void combine_apply2f(const float* __restrict__ inp, const float* __restrict__ divisor,
                                const bf16* __restrict__ h0, const bf16* __restrict__ h1,
                                const float* __restrict__ partials, bf16* __restrict__ y) {
    int idx = blockIdx.x * 256 + threadIdx.x;
    int s = idx & (S_ - 1);
    int t = idx / S_;
    int fc = t % NC_;
    int b = t / NC_;
    float acc = 0.f;
    const float* pp = partials + (size_t)b * NC_ * S_ + s;
    for (int c = 0; c < fc; ++c) acc += pp[(size_t)c * S_];
    size_t base = (size_t)b * F_ * S_ + (size_t)(fc * FC_) * S_ + s;
#pragma unroll 4
    for (int f = 0; f < FC_; ++f) {
        size_t o = base + (size_t)f * S_;
        float dep = __bfloat162float(h0[o]) + __bfloat162float(h1[o]);
        float poi = __bfloat162float(h0[o + BFS_]) + __bfloat162float(h1[o + BFS_]);
        float shi = __bfloat162float(h0[o + 2 * BFS_]) + __bfloat162float(h1[o + 2 * BFS_]);
        acc += dep;
        float yv = inp[o] * (acc / divisor[fc * FC_ + f] + poi) + shi;
        y[o] = __float2bfloat16(yv);
    }
}

__global__ void finalnorm(const float* __restrict__ y, const float2* __restrict__ stats,
                          float* __restrict__ out) {
    size_t i = (size_t)blockIdx.x * 256 + threadIdx.x;
    if (i >= (size_t)B_ * F_ * S_) return;
    float2 st = stats[i / S_];
    float v = fmaxf(y[i], 0.f);
    out[i] = (v - st.x) * st.y;
}

// bf16-y variant, 8 elems/thread
__global__ void finalnorm_bf(const bf16* __restrict__ y, const float2* __restrict__ stats,
                             float* __restrict__ out) {
    size_t i8 = (size_t)blockIdx.x * 256 + threadIdx.x;   // over BFS/8
    size_t row = i8 >> 8;                                  // S/8 = 256 chunks per row
    float2 st = stats[row];
    s16x8 v = ((const s16x8*)y)[i8];
    float* o = out + i8 * 8;
#pragma unroll
    for (int e = 0; e < 8; ++e) {
        float f = fmaxf(bf2f((unsigned short)v[e]), 0.f);
        o[e] = (f - st.x) * st.y;
    }
}

// ---------------------------------------------------------------------------
extern "C" void kernel_launch(void* const* d_in, const int* in_sizes, int n_in,
                              void* d_out, int out_size, void* d_ws, size_t ws_size,
                              hipStream_t stream) {
    const float* inp = (const float*)d_in[0];
    const float* pos = (const float*)d_in[1];
    const float* divisor = (const float*)d_in[2];
    const float* w[6] = { (const float*)d_in[3], (const float*)d_in[4],
                          (const float*)d_in[5], (const float*)d_in[6],
                          (const float*)d_in[7], (const float*)d_in[8] };
    float* out = (float*)d_out;

    size_t off = 0;
    auto alloc = [&](size_t bytes) {
        off = (off + 255) & ~(size_t)255;
        void* r = (char*)d_ws + off;
        off += bytes;
        return r;
    };

    const size_t needB = ((BSPF_ * 2 + 255) & ~255UL)
                       + ((3 * BSPF_ * 2 + 255) & ~255UL)
                       + ((3 * 7 * FF_ * 2 + 255) & ~255UL)
                       + ((3 * BFS_ * 2 + 255) & ~255UL)
                       + ((3 * BFS_ * 2 + 255) & ~255UL)
                       + ((3 * B_ * F_ * 8 + 255) & ~255UL)
                       + ((B_ * NC_ * S_ * 4 + 255) & ~255UL)
                       + 4096;
    const size_t needC = needB + ((3 * BFS_ * 2 + 255) & ~255UL);   // + split-K partials
    const size_t needD = needC + ((BFS_ * 2 + 255) & ~255UL);       // + bf16 inp copy

    if (ws_size >= needB) {
        const bool splitK = (ws_size >= needC);
        const bool haveInpb = (ws_size >= needD);
        // NOTE: allocation ORDER matters — conv_gemm8's B staging overreads up
        // to 58 rows past a slab end (never consumed); xT overflow lands in
        // hT3, hT3 overflow lands in Wb3. Keep xT -> hT3 -> Wb3 adjacency.
        bf16* xT   = (bf16*)alloc(BSPF_ * 2);
        bf16* hT3  = (bf16*)alloc(3 * BSPF_ * 2);
        bf16* Wb3  = (bf16*)alloc(3 * 7 * FF_ * 2);
        bf16* O3   = (bf16*)alloc(3 * BFS_ * 2);
        bf16* br3  = (bf16*)alloc(3 * BFS_ * 2);
        float2* stats3 = (float2*)alloc(3 * B_ * F_ * 8);
        float* partials = (float*)alloc(B_ * NC_ * S_ * 4);
        bf16* P0 = splitK ? (bf16*)alloc(3 * BFS_ * 2) : nullptr;
        bf16* inpb = haveInpb ? (bf16*)alloc(BFS_ * 2) : nullptr;

        zero_pads<<<(4 * B_ * (K_ - 1) * F_ + 255) / 256, 256, 0, stream>>>(xT, hT3, 3);
        prep_x<<<dim3(S_ / 64, F_ / 64, B_), 256, 0, stream>>>(inp, pos, xT, inpb);

        wconv3<<<dim3(F_ * F_ / 256, 3), 256, 0, stream>>>(w[0], w[2], w[4], Wb3);
        if (splitK) {
            conv_gemm8<true><<<768, 512, 0, stream>>>(Wb3, xT, P0, O3, 7 * FF_, 0, BFS_);
            addb_stats<<<3 * B_ * F_ / 4, 256, 0, stream>>>(P0, O3, stats3);
        } else {
            conv_gemm8<false><<<384, 512, 0, stream>>>(Wb3, xT, O3, O3, 7 * FF_, 0, BFS_);
            rowstats_bf16<<<3 * B_ * F_ / 4, 256, 0, stream>>>(O3, stats3);
        }
        normT<<<dim3(S_ / 64, F_ / 64, 12), 256, 0, stream>>>(O3, stats3, hT3);

        wconv3<<<dim3(F_ * F_ / 256, 3), 256, 0, stream>>>(w[1], w[3], w[5], Wb3);
        if (splitK) {
            conv_gemm8<true><<<768, 512, 0, stream>>>(Wb3, hT3, P0, br3, 7 * FF_, BSPF_, BFS_);
            bf16* ybf = O3;   // O3 dead after normT
            combine_partial2<<<B_ * NC_ * S_ / 256, 256, 0, stream>>>(P0, br3, partials);
            if (haveInpb)
                combine_apply2<<<B_ * NC_ * S_ / 256, 256, 0, stream>>>(
                    inpb, divisor, P0, br3, partials, ybf);
            else
                combine_apply2f<<<B_ * NC_ * S_ / 256, 256, 0, stream>>>(
                    inp, divisor, P0, br3, partials, ybf);
            rowstats_bf16<<<B_ * F_ / 4, 256, 0, stream>>>(ybf, stats3);
            finalnorm_bf<<<(int)(BFS_ / 8 / 256), 256, 0, stream>>>(ybf, stats3, out);
        } else {
            conv_gemm8<false><<<384, 512, 0, stream>>>(Wb3, hT3, br3, br3, 7 * FF_, BSPF_, BFS_);
            float* ybuf = (float*)O3;
            combine_partial<<<B_ * NC_ * S_ / 256, 256, 0, stream>>>(br3, partials);
            combine_apply<<<B_ * NC_ * S_ / 256, 256, 0, stream>>>(
                inp, divisor, br3, br3 + BFS_, br3 + 2 * BFS_, partials, ybuf);
            rowstats_f32<<<B_ * F_ / 4, 256, 0, stream>>>(ybuf, stats3);
            finalnorm<<<(B_ * F_ * S_) / 256, 256, 0, stream>>>(ybuf, stats3, out);
        }
    } else {
        // sequential fallback (compact ws), proven path
        bf16* xT   = (bf16*)alloc(BSPF_ * 2);
        bf16* hT1  = (bf16*)alloc(BSPF_ * 2);
        bf16* Wb1  = (bf16*)alloc(7 * FF_ * 2);
        bf16* O1   = (bf16*)alloc(BFS_ * 2);
        bf16* br3  = (bf16*)alloc(3 * BFS_ * 2);
        float2* stats3 = (float2*)alloc(B_ * F_ * 8);
        float* partials = (float*)alloc(B_ * NC_ * S_ * 4);
        float* ybuf = (float*)xT;

        zero_pads<<<(2 * B_ * (K_ - 1) * F_ + 255) / 256, 256, 0, stream>>>(xT, hT1, 1);
        prep_x<<<dim3(S_ / 64, F_ / 64, B_), 256, 0, stream>>>(inp, pos, xT, nullptr);

        for (int j = 0; j < 3; ++j) {
            wconv<<<F_ * F_ / 256, 256, 0, stream>>>(w[2 * j], Wb1);
            conv_gemm_small<<<16 * 8 * 4, 256, 0, stream>>>(Wb1, xT, O1);
            rowstats_bf16<<<B_ * F_ / 4, 256, 0, stream>>>(O1, stats3);
            normT<<<dim3(S_ / 64, F_ / 64, 4), 256, 0, stream>>>(O1, stats3, hT1);
            wconv<<<F_ * F_ / 256, 256, 0, stream>>>(w[2 * j + 1], Wb1);
            conv_gemm_small<<<16 * 8 * 4, 256, 0, stream>>>(Wb1, hT1, br3 + j * BFS_);
        }
        combine_partial<<<B_ * NC_ * S_ / 256, 256, 0, stream>>>(br3, partials);
        combine_apply<<<B_ * NC_ * S_ / 256, 256, 0, stream>>>(
            inp, divisor, br3, br3 + BFS_, br3 + 2 * BFS_, partials, ybuf);
        rowstats_f32<<<B_ * F_ / 4, 256, 0, stream>>>(ybuf, stats3);
        finalnorm<<<(B_ * F_ * S_) / 256, 256, 0, stream>>>(ybuf, stats3, out);
    }
}

// Round 11
// 677.031 us; speedup vs baseline: 1.1185x; 1.0084x over previous
//
#include <hip/hip_runtime.h>
#include <hip/hip_bf16.h>
#include <stdint.h>

#define B_ 4
#define F_ 1024
#define S_ 2048
#define K_ 7
#define SP_ (S_ + K_ - 1)   // 2054 padded rows (6 zero rows at the front)
#define FC_ 64              // cumsum chunk size
#define NC_ (F_ / FC_)      // 16 chunks
#define FF_ ((size_t)F_ * F_)
#define BFS_ ((size_t)B_ * F_ * S_)
#define BSPF_ ((size_t)B_ * SP_ * F_)

using f32x4 = __attribute__((ext_vector_type(4))) float;
using s16x8 = __attribute__((ext_vector_type(8))) short;
using bf16 = __hip_bfloat16;

// -------- async global->LDS 16B (wave-uniform base + lane*16 semantics) -----
typedef const __attribute__((address_space(1))) void gvoid_t;
typedef __attribute__((address_space(3))) void lvoid_t;
__device__ __forceinline__ void async16(const void* g, void* l) {
    __builtin_amdgcn_global_load_lds((gvoid_t*)g, (lvoid_t*)l, 16, 0, 0);
}

__device__ __forceinline__ float bf2f(unsigned short u) {
    union { unsigned int i; float f; } c; c.i = ((unsigned int)u) << 16; return c.f;
}

#define FENCE() asm volatile("" ::: "memory")
#define BARRIER() do { FENCE(); __builtin_amdgcn_s_barrier(); FENCE(); } while (0)

// ---------------------------------------------------------------------------
__global__ void zero_pads(bf16* xT, bf16* hT, int nh) {
    int i = blockIdx.x * 256 + threadIdx.x;
    const int per = B_ * (K_ - 1) * F_;
    int total = (1 + nh) * per;
    if (i >= total) return;
    int r = i / per, o = i % per;
    int b = o / ((K_ - 1) * F_);
    int rr = o % ((K_ - 1) * F_);
    bf16 z = __float2bfloat16(0.0f);
    if (r == 0) xT[(size_t)b * SP_ * F_ + rr] = z;
    else        hT[(size_t)(r - 1) * BSPF_ + (size_t)b * SP_ * F_ + rr] = z;
}

// out = inp + pos_embd transposed to xT; optionally also emit bf16 copy of inp
__global__ void prep_x(const float* __restrict__ inp, const float* __restrict__ pos,
                       bf16* __restrict__ xT, bf16* __restrict__ inpb) {
    __shared__ bf16 tile[64][66];
    int b = blockIdx.z;
    int f0 = blockIdx.y * 64, s0 = blockIdx.x * 64;
    int tj = threadIdx.x & 63;
    int t4 = threadIdx.x >> 6;
#pragma unroll
    for (int r = 0; r < 16; ++r) {
        int i = r * 4 + t4;
        size_t off = (size_t)(f0 + i) * S_ + s0 + tj;
        float vi = inp[(size_t)b * F_ * S_ + off];
        if (inpb) inpb[(size_t)b * F_ * S_ + off] = __float2bfloat16(vi);
        tile[i][tj] = __float2bfloat16(vi + pos[off]);
    }
    __syncthreads();
#pragma unroll
    for (int r = 0; r < 16; ++r) {
        int j = r * 4 + t4;
        xT[(size_t)b * SP_ * F_ + (size_t)(6 + s0 + j) * F_ + f0 + tj] = tile[tj][j];
    }
}

// single-weight repack (sequential fallback)
__global__ void wconv(const float* __restrict__ w, bf16* __restrict__ wt) {
    int i = blockIdx.x * 256 + threadIdx.x;
    if (i >= F_ * F_) return;
    const float* src = w + (size_t)i * K_;
#pragma unroll
    for (int t = 0; t < K_; ++t)
        wt[(size_t)t * FF_ + i] = __float2bfloat16(src[t]);
}

// batched 3-weight repack: grid (FF/256, 3)
__global__ void wconv3(const float* __restrict__ w0, const float* __restrict__ w1,
                       const float* __restrict__ w2, bf16* __restrict__ wt) {
    int i = blockIdx.x * 256 + threadIdx.x;
    int z = blockIdx.y;
    const float* w = (z == 0) ? w0 : (z == 1 ? w1 : w2);
    bf16* dst = wt + (size_t)z * 7 * FF_;
    const float* src = w + (size_t)i * K_;
#pragma unroll
    for (int t = 0; t < K_; ++t)
        dst[(size_t)t * FF_ + i] = __float2bfloat16(src[t]);
}

// ---------------------------------------------------------------------------
// 256x256 bf16 conv-GEMM, BK=64, 8-phase schedule, kb-major K-order with
// SHARED B-panel across the 7 taps (tap = shifted LDS read). LDS 144 KiB.
// R10: zero-register read rebalance — bfr split into bfA(nh0)/bfB(nh1);
// ph4 prefetches NEXT tap's nh0 into bfA (dead after ph3), nh1 read moves
// ph2->ph1. Read balance 12/4/8/0 -> 12/0/8/4-hidden; barriers/vmcnt/staging
// byte-identical to the proven 297.9us R6 kernel.
#define MFMA_QUAD(MB, NB, BR)                                                    \
    __builtin_amdgcn_s_setprio(1);                                               \
    _Pragma("unroll")                                                            \
    for (int kk = 0; kk < 2; ++kk) {                                             \
        _Pragma("unroll")                                                        \
        for (int m = 0; m < 4; ++m) {                                            \
            _Pragma("unroll")                                                    \
            for (int n = 0; n < 2; ++n) {                                        \
                acc[(MB) + m][(NB) + n] = __builtin_amdgcn_mfma_f32_16x16x32_bf16( \
                    af[m][kk], BR[n][kk], acc[(MB) + m][(NB) + n], 0, 0, 0);     \
            }                                                                    \
        }                                                                        \
    }                                                                            \
    __builtin_amdgcn_s_setprio(0)

template <bool SPLIT>
__global__ __launch_bounds__(512, 2)
void conv_gemm8(const bf16* __restrict__ Wbase, const bf16* __restrict__ Xbase,
                bf16* __restrict__ O0, bf16* __restrict__ O1,
                long wStride, long xStride, long oStride) {
    __shared__ __align__(16) char lds[147456];

    // bijective XCD swizzle (gridDim.x % 8 == 0)
    int wg = blockIdx.x;
    int nchunk = gridDim.x >> 3;
    int swz = (wg & 7) * nchunk + (wg >> 3);
    int kp, r;
    if (SPLIT) { kp = swz & 1; r = swz >> 1; } else { kp = 0; r = swz; }
    int nt = r & 7;             // S/256
    int mt = (r >> 3) & 3;      // F/256
    int z  = r >> 5;            // j*4 + b
    int j = z >> 2, b = z & 3;
    const int kb0 = kp * 8;
    const int kbN = SPLIT ? 8 : 16;
    const int NTp = kbN * 7;

    const bf16* Wbr = Wbase + (size_t)j * wStride;                        // [7][F][F]
    const bf16* Xbr = Xbase + (size_t)j * xStride + (size_t)b * SP_ * F_; // [SP][F]
    bf16* out = (kp ? O1 : O0) + (size_t)j * oStride + (size_t)b * F_ * S_;
    const int m0 = mt * 256, n0 = nt * 256;

    const int tid = threadIdx.x;
    const int lane = tid & 63, wid = tid >> 6;
    const int wm = wid >> 2, wn = wid & 3;      // wave tile: rows wm*128, cols wn*64

    // ---- staging decode: linear LDS byte -> source element offset (inverse swizzle)
    const int tid16 = tid * 16;
    const int p0 = tid16, p1 = 8192 + tid16;
    const int lp0 = p0 ^ (((p0 >> 9) & 1) << 5);
    const int lp1 = p1 ^ (((p1 >> 9) & 1) << 5);
    const int stgO0 = (((lp0 >> 11) << 4) + ((lp0 >> 6) & 15)) * F_
                    + (((lp0 >> 10) & 1) << 5) + ((lp0 & 63) >> 1);
    const int stgO1 = (((lp1 >> 11) << 4) + ((lp1 >> 6) & 15)) * F_
                    + (((lp1 >> 10) & 1) << 5) + ((lp1 & 63) >> 1);
    // B piece decode: piece pc covers 64 rows; src elem = bsrc + pc*64*F
    const int bsrc = (((tid16 >> 11) << 4) + ((lp0 >> 6) & 15)) * F_
                   + (((lp0 >> 10) & 1) << 5) + ((lp0 & 63) >> 1);

    // ---- ds_read swizzled offsets
    const int rA = lane & 15, cA = (lane >> 4) * 8;
    const int swzRC = (rA << 6) + ((cA << 1) ^ (((rA >> 3) & 1) << 5));
    const int aOffBase = wm * 16384 + swzRC;
    int addrB[7];
#pragma unroll
    for (int t = 0; t < 7; ++t) {
        int R = wn * 64 + rA + t;           // shifted B row (tap t)
        addrB[t] = ((R >> 4) << 11) + ((R & 15) << 6)
                 + ((cA << 1) ^ (((R >> 3) & 1) << 5));
    }

    f32x4 acc[8][4] = {};
    s16x8 af[4][2], bfA[2][2], bfB[2][2];

    auto STGA = [&](int regionByte, const bf16* src) {   // 16KB region, 2 loads
        async16(src + stgO0, lds + regionByte + tid16);
        async16(src + stgO1, lds + regionByte + 8192 + tid16);
    };
    auto STGB = [&](int kb1, int pc) {                   // 8KB piece, 1 load
        const bf16* src = Xbr + (size_t)n0 * F_ + kb1 * 64 + bsrc + pc * 64 * F_;
        async16(src, lds + 65536 + (kb1 & 1) * 40960 + pc * 8192 + tid16);
    };
    auto ASRC = [&](int kb, int t, int h) {
        return Wbr + (size_t)t * FF_ + (size_t)(m0 + h * 128) * F_ + kb * 64;
    };

    // ---- prologue: B(kb0) whole, A(kt0) both halves, A0(kt1). keep-2 = A0(kt1)
    STGB(kb0, 0); STGB(kb0, 1); STGB(kb0, 2); STGB(kb0, 3); STGB(kb0, 4);
    STGA(0,     ASRC(kb0, 0, 0));     // A0(kt0) bufA0
    STGA(16384, ASRC(kb0, 0, 1));     // A1(kt0) bufA0
    STGA(32768, ASRC(kb0, 1, 0));     // A0(kt1) bufA1
    asm volatile("s_waitcnt vmcnt(2)" ::: "memory");
    BARRIER();

    // pre-load nh0 of (kb0, tap 0) — B(kb0) pieces drained by prologue vmcnt+barrier
    {
        const char* lb0 = lds + 65536 + (kb0 & 1) * 40960 + addrB[0];
#pragma unroll
        for (int n = 0; n < 2; ++n) {
            bfA[n][0] = *(const s16x8*)(lb0 + n * 2048);
            bfA[n][1] = *(const s16x8*)(lb0 + n * 2048 + 1024);
        }
    }

    for (int kb = kb0; kb < kb0 + kbN; ++kb) {
        const int bBo = 65536 + (kb & 1) * 40960;
#pragma unroll
        for (int t = 0; t < 7; ++t) {
            const int ktl = (kb - kb0) * 7 + t;
            const int pA = (kb + t) & 1;                 // (kb*7+t)&1
            const char* la = lds + pA * 32768 + aOffBase;
            const char* lb = lds + bBo + addrB[t];
            const int t1 = (t == 6) ? 0 : t + 1;         // kt+1 decomposition
            const int kb1 = (t == 6) ? kb + 1 : kb;
            const int t2 = (t >= 5) ? t - 5 : t + 2;     // kt+2 decomposition
            const int kb2 = (t >= 5) ? kb + 1 : kb;
            const bool bstage = (t >= 1 && t <= 5) && (kb - kb0) < kbN - 1;
            // next-tap B base (nh0 prefetch target address)
            const char* lbN = (t == 6)
                ? lds + 65536 + ((kb + 1) & 1) * 40960 + addrB[0]
                : lds + bBo + addrB[t + 1];

            // ---- phase 1: read A-mh0 + B-nh1(current); stage A1(kt+1)
#pragma unroll
            for (int m = 0; m < 4; ++m) {
                af[m][0] = *(const s16x8*)(la + m * 2048);
                af[m][1] = *(const s16x8*)(la + m * 2048 + 1024);
            }
#pragma unroll
            for (int n = 0; n < 2; ++n) {
                bfB[n][0] = *(const s16x8*)(lb + (2 + n) * 2048);
                bfB[n][1] = *(const s16x8*)(lb + (2 + n) * 2048 + 1024);
            }
            if (ktl + 1 < NTp) STGA((pA ^ 1) * 32768 + 16384, ASRC(kb1, t1, 1));
            BARRIER();
            MFMA_QUAD(0, 0, bfA);
            BARRIER();

            // ---- phase 2: no ds_reads; stage one B(kb+1) piece (t=1..5)
            if (bstage) STGB(kb + 1, t - 1);
            BARRIER();
            MFMA_QUAD(0, 2, bfB);
            BARRIER();

            // ---- phase 3: read A-mh1
#pragma unroll
            for (int m = 0; m < 4; ++m) {
                af[m][0] = *(const s16x8*)(la + (4 + m) * 2048);
                af[m][1] = *(const s16x8*)(la + (4 + m) * 2048 + 1024);
            }
            BARRIER();
            MFMA_QUAD(4, 0, bfA);
            BARRIER();

            // ---- phase 4: stage A0(kt+2); prefetch next-tap nh0 into bfA
            //      (bfA dead after ph3; consumed next kt ph1); MFMA; counted vmcnt
            if (ktl + 2 < NTp) STGA(pA * 32768, ASRC(kb2, t2, 0));
            if (ktl + 1 < NTp) {
#pragma unroll
                for (int n = 0; n < 2; ++n) {
                    bfA[n][0] = *(const s16x8*)(lbN + n * 2048);
                    bfA[n][1] = *(const s16x8*)(lbN + n * 2048 + 1024);
                }
            }
            MFMA_QUAD(4, 2, bfB);
            if (ktl < NTp - 2) {
                if (bstage) { asm volatile("s_waitcnt vmcnt(3)" ::: "memory"); }
                else        { asm volatile("s_waitcnt vmcnt(2)" ::: "memory"); }
            } else {
                asm volatile("s_waitcnt vmcnt(0)" ::: "memory");
            }
            BARRIER();
        }
    }

    // epilogue: C/D layout col=lane&15, row=(lane>>4)*4+reg  [m89-verified]
    const int cm = (lane >> 4) * 4, cn = lane & 15;
#pragma unroll
    for (int mf = 0; mf < 8; ++mf)
#pragma unroll
        for (int nf = 0; nf < 4; ++nf)
#pragma unroll
            for (int r2 = 0; r2 < 4; ++r2) {
                int rr = m0 + wm * 128 + mf * 16 + cm + r2;
                int cc = n0 + wn * 64 + nf * 16 + cn;
                out[(size_t)rr * S_ + cc] = __float2bfloat16(acc[mf][nf][r2]);
            }
}

// d += a (bf16, row-wise), AND compute relu row-stats of the sum in one pass.
__global__ void addb_stats(const bf16* __restrict__ a, bf16* __restrict__ d,
                           float2* __restrict__ stats) {
    int row = blockIdx.x * 4 + (threadIdx.x >> 6);
    int lane = threadIdx.x & 63;
    const s16x8* pa = (const s16x8*)(a + (size_t)row * S_);
    s16x8* pd = (s16x8*)(d + (size_t)row * S_);
    float s1 = 0.f, s2 = 0.f;
#pragma unroll
    for (int q = 0; q < S_ / 512; ++q) {
        s16x8 va = pa[q * 64 + lane];
        s16x8 vd = pd[q * 64 + lane];
        s16x8 o;
#pragma unroll
        for (int e = 0; e < 8; ++e) {
            float f = bf2f((unsigned short)va[e]) + bf2f((unsigned short)vd[e]);
            bf16 h = __float2bfloat16(f);
            o[e] = (short)__bfloat16_as_ushort(h);
            float rr = fmaxf(__bfloat162float(h), 0.f);
            s1 += rr; s2 += rr * rr;
        }
        pd[q * 64 + lane] = o;
    }
#pragma unroll
    for (int dd = 32; dd; dd >>= 1) { s1 += __shfl_xor(s1, dd); s2 += __shfl_xor(s2, dd); }
    if (lane == 0) {
        float m = s1 / (float)S_;
        float ss = fmaxf(s2 - (float)S_ * m * m, 0.f);
        float denom = (sqrtf(ss) + 1e-5f) * (1.0f / sqrtf((float)S_));
        stats[row] = make_float2(m, 1.0f / denom);
    }
}

// ---------------- fallback 128x128 2-phase GEMM (small-ws path) -------------
__global__ void conv_gemm_small(const bf16* __restrict__ W7, const bf16* __restrict__ xT,
                                bf16* __restrict__ out) {
    __shared__ bf16 tA[128][64];
    __shared__ bf16 tB[128][64];
    int wg = blockIdx.x;
    int cpx = gridDim.x >> 3;
    int swz = (wg & 7) * cpx + (wg >> 3);
    int sx = swz & 15;
    int t1 = swz >> 4;
    int sy = t1 & 7;
    int b = t1 >> 3;
    const bf16* Xbr = xT + (size_t)b * SP_ * F_;
    bf16* ob = out + (size_t)b * F_ * S_;
    int m0 = sy * 128, n0 = sx * 128;
    int tid = threadIdx.x;
    int lane = tid & 63, wid = tid >> 6;
    int wm = wid >> 1, wn = wid & 1;
    f32x4 acc[4][4] = {};
    int srow = tid >> 3, cpart = tid & 7;
    for (int t = 0; t < K_; ++t) {
        const bf16* Wt = W7 + (size_t)t * FF_ + (size_t)m0 * F_;
        const bf16* Xt = Xbr + (size_t)(n0 + t) * F_;
        for (int kb = 0; kb < F_ / 64; ++kb) {
            const bf16* wa = Wt + kb * 64 + cpart * 8;
            const bf16* xa = Xt + kb * 64 + cpart * 8;
#pragma unroll
            for (int q = 0; q < 4; ++q) async16(wa + (size_t)(q * 32 + srow) * F_, &tA[q * 32 + srow][cpart * 8]);
#pragma unroll
            for (int q = 0; q < 4; ++q) async16(xa + (size_t)(q * 32 + srow) * F_, &tB[q * 32 + srow][cpart * 8]);
            __syncthreads();
#pragma unroll
            for (int kk = 0; kk < 2; ++kk) {
                int krow = kk * 32 + (lane >> 4) * 8;
                s16x8 a2[4], b2[4];
#pragma unroll
                for (int m = 0; m < 4; ++m) a2[m] = *(const s16x8*)&tA[wm * 64 + m * 16 + (lane & 15)][krow];
#pragma unroll
                for (int n = 0; n < 4; ++n) b2[n] = *(const s16x8*)&tB[wn * 64 + n * 16 + (lane & 15)][krow];
#pragma unroll
                for (int m = 0; m < 4; ++m)
#pragma unroll
                    for (int n = 0; n < 4; ++n)
                        acc[m][n] = __builtin_amdgcn_mfma_f32_16x16x32_bf16(a2[m], b2[n], acc[m][n], 0, 0, 0);
            }
            __syncthreads();
        }
    }
    int cm = (lane >> 4) * 4, cn = lane & 15;
#pragma unroll
    for (int m = 0; m < 4; ++m)
#pragma unroll
        for (int n = 0; n < 4; ++n)
#pragma unroll
            for (int r = 0; r < 4; ++r)
                ob[(size_t)(m0 + wm * 64 + m * 16 + cm + r) * S_ + n0 + wn * 64 + n * 16 + cn] =
                    __float2bfloat16(acc[m][n][r]);
}

// ---------------------------------------------------------------------------
__global__ void rowstats_bf16(const bf16* __restrict__ x, float2* __restrict__ stats) {
    int row = blockIdx.x * 4 + (threadIdx.x >> 6);
    int lane = threadIdx.x & 63;
    const bf16* p = x + (size_t)row * S_;
    float s1 = 0.f, s2 = 0.f;
#pragma unroll
    for (int q = 0; q < S_ / 512; ++q) {
        s16x8 v = *(const s16x8*)(p + q * 512 + lane * 8);
#pragma unroll
        for (int e = 0; e < 8; ++e) {
            float f = fmaxf(bf2f((unsigned short)v[e]), 0.f);
            s1 += f; s2 += f * f;
        }
    }
#pragma unroll
    for (int d = 32; d; d >>= 1) { s1 += __shfl_xor(s1, d); s2 += __shfl_xor(s2, d); }
    if (lane == 0) {
        float m = s1 / (float)S_;
        float ss = fmaxf(s2 - (float)S_ * m * m, 0.f);
        float denom = (sqrtf(ss) + 1e-5f) * (1.0f / sqrtf((float)S_));
        stats[row] = make_float2(m, 1.0f / denom);
    }
}

__global__ void rowstats_f32(const float* __restrict__ x, float2* __restrict__ stats) {
    int row = blockIdx.x * 4 + (threadIdx.x >> 6);
    int lane = threadIdx.x & 63;
    const float* p = x + (size_t)row * S_;
    float s1 = 0.f, s2 = 0.f;
#pragma unroll
    for (int q = 0; q < S_; q += 256) {
        float4 v = *(const float4*)(p + q + lane * 4);
        float a = fmaxf(v.x, 0.f), bb = fmaxf(v.y, 0.f);
        float c = fmaxf(v.z, 0.f), d = fmaxf(v.w, 0.f);
        s1 += a + bb + c + d;
        s2 += a * a + bb * bb + c * c + d * d;
    }
#pragma unroll
    for (int d = 32; d; d >>= 1) { s1 += __shfl_xor(s1, d); s2 += __shfl_xor(s2, d); }
    if (lane == 0) {
        float m = s1 / (float)S_;
        float ss = fmaxf(s2 - (float)S_ * m * m, 0.f);
        float denom = (sqrtf(ss) + 1e-5f) * (1.0f / sqrtf((float)S_));
        stats[row] = make_float2(m, 1.0f / denom);
    }
}

__global__ void normT(const bf16* __restrict__ x, const float2* __restrict__ stats,
                      bf16* __restrict__ hT) {
    __shared__ bf16 tile[64][72];
    int z = blockIdx.z;
    int f0 = blockIdx.y * 64, s0 = blockIdx.x * 64;
    const bf16* xb = x + (size_t)z * F_ * S_;
    bf16* hb = hT + (size_t)z * SP_ * F_;
    const float2* st = stats + (size_t)z * F_;
    int i = threadIdx.x >> 3;
    int c8 = threadIdx.x & 7;
#pragma unroll
    for (int p = 0; p < 2; ++p) {
        int r = i + p * 32;
        float2 s = st[f0 + r];
        s16x8 v = *(const s16x8*)(xb + (size_t)(f0 + r) * S_ + s0 + c8 * 8);
#pragma unroll
        for (int e = 0; e < 8; ++e) {
            float f = fmaxf(bf2f((unsigned short)v[e]), 0.f);
            tile[r][c8 * 8 + e] = __float2bfloat16((f - s.x) * s.y);
        }
    }
    __syncthreads();
    int tj = threadIdx.x & 63;
    int t4 = threadIdx.x >> 6;
#pragma unroll
    for (int r = 0; r < 16; ++r) {
        int jrow = r * 4 + t4;
        hb[(size_t)(6 + s0 + jrow) * F_ + f0 + tj] = tile[tj][jrow];
    }
}

// ---- cumsum/combine: plain (fallback) and split-K fused (2-buffer) variants
__global__ void combine_partial(const bf16* __restrict__ depth,
                                float* __restrict__ partials) {
    int idx = blockIdx.x * 256 + threadIdx.x;
    int s = idx & (S_ - 1);
    int t = idx / S_;
    int fc = t % NC_;
    int b = t / NC_;
    const bf16* p = depth + (size_t)b * F_ * S_ + (size_t)(fc * FC_) * S_ + s;
    float acc = 0.f;
#pragma unroll
    for (int f = 0; f < FC_; ++f) acc += __bfloat162float(p[(size_t)f * S_]);
    partials[idx] = acc;
}

__global__ void combine_partial2(const bf16* __restrict__ dA, const bf16* __restrict__ dB,
                                 float* __restrict__ partials) {
    int idx = blockIdx.x * 256 + threadIdx.x;
    int s = idx & (S_ - 1);
    int t = idx / S_;
    int fc = t % NC_;
    int b = t / NC_;
    size_t base = (size_t)b * F_ * S_ + (size_t)(fc * FC_) * S_ + s;
    float acc = 0.f;
#pragma unroll
    for (int f = 0; f < FC_; ++f) {
        size_t o = base + (size_t)f * S_;
        acc += __bfloat162float(dA[o]) + __bfloat162float(dB[o]);
    }
    partials[idx] = acc;
}

__global__ void combine_apply(const float* __restrict__ inp, const float* __restrict__ divisor,
                              const bf16* __restrict__ depth, const bf16* __restrict__ point,
                              const bf16* __restrict__ shiftb,
                              const float* __restrict__ partials, float* __restrict__ y) {
    int idx = blockIdx.x * 256 + threadIdx.x;
    int s = idx & (S_ - 1);
    int t = idx / S_;
    int fc = t % NC_;
    int b = t / NC_;
    float acc = 0.f;
    const float* pp = partials + (size_t)b * NC_ * S_ + s;
    for (int c = 0; c < fc; ++c) acc += pp[(size_t)c * S_];
    size_t base = (size_t)b * F_ * S_ + (size_t)(fc * FC_) * S_ + s;
#pragma unroll 4
    for (int f = 0; f < FC_; ++f) {
        size_t o = base + (size_t)f * S_;
        acc += __bfloat162float(depth[o]);
        float yv = inp[o] * (acc / divisor[fc * FC_ + f] + __bfloat162float(point[o]))
                 + __bfloat162float(shiftb[o]);
        y[o] = yv;
    }
}

// split-K fused: branches as two halves h0/h1 [3][B][F][S]; inp as bf16; y bf16
__global__ void combine_apply2(const bf16* __restrict__ inpb, const float* __restrict__ divisor,
                               const bf16* __restrict__ h0, const bf16* __restrict__ h1,
                               const float* __restrict__ partials, bf16* __restrict__ y) {
    int idx = blockIdx.x * 256 + threadIdx.x;
    int s = idx & (S_ - 1);
    int t = idx / S_;
    int fc = t % NC_;
    int b = t / NC_;
    float acc = 0.f;
    const float* pp = partials + (size_t)b * NC_ * S_ + s;
    for (int c = 0; c < fc; ++c) acc += pp[(size_t)c * S_];
    size_t base = (size_t)b * F_ * S_ + (size_t)(fc * FC_) * S_ + s;
#pragma unroll 4
    for (int f = 0; f < FC_; ++f) {
        size_t o = base + (size_t)f * S_;
        float dep = __bfloat162float(h0[o]) + __bfloat162float(h1[o]);
        float poi = __bfloat162float(h0[o + BFS_]) + __bfloat162float(h1[o + BFS_]);
        float shi = __bfloat162float(h0[o + 2 * BFS_]) + __bfloat162float(h1[o + 2 * BFS_]);
        acc += dep;
        float yv = __bfloat162float(inpb[o]) * (acc / divisor[fc * FC_ + f] + poi) + shi;
        y[o] = __float2bfloat16(yv);
    }
}

// f32-inp variant (used when ws lacks room for inpb)
__global__ void combine_apply2f(const float* __restrict__ inp, const float* __restrict__ divisor,
                                const bf16* __restrict__ h0, const bf16* __restrict__ h1,
                                const float* __restrict__ partials, bf16* __restrict__ y) {
    int idx = blockIdx.x * 256 + threadIdx.x;
    int s = idx & (S_ - 1);
    int t = idx / S_;
    int fc = t % NC_;
    int b = t / NC_;
    float acc = 0.f;
    const float* pp = partials + (size_t)b * NC_ * S_ + s;
    for (int c = 0; c < fc; ++c) acc += pp[(size_t)c * S_];
    size_t base = (size_t)b * F_ * S_ + (size_t)(fc * FC_) * S_ + s;
#pragma unroll 4
    for (int f = 0; f < FC_; ++f) {
        size_t o = base + (size_t)f * S_;
        float dep = __bfloat162float(h0[o]) + __bfloat162float(h1[o]);
        float poi = __bfloat162float(h0[o + BFS_]) + __bfloat162float(h1[o + BFS_]);
        float shi = __bfloat162float(h0[o + 2 * BFS_]) + __bfloat162float(h1[o + 2 * BFS_]);
        acc += dep;
        float yv = inp[o] * (acc / divisor[fc * FC_ + f] + poi) + shi;
        y[o] = __float2bfloat16(yv);
    }
}

__global__ void finalnorm(const float* __restrict__ y, const float2* __restrict__ stats,
                          float* __restrict__ out) {
    size_t i = (size_t)blockIdx.x * 256 + threadIdx.x;
    if (i >= (size_t)B_ * F_ * S_) return;
    float2 st = stats[i / S_];
    float v = fmaxf(y[i], 0.f);
    out[i] = (v - st.x) * st.y;
}

// bf16-y variant, 8 elems/thread
__global__ void finalnorm_bf(const bf16* __restrict__ y, const float2* __restrict__ stats,
                             float* __restrict__ out) {
    size_t i8 = (size_t)blockIdx.x * 256 + threadIdx.x;   // over BFS/8
    size_t row = i8 >> 8;                                  // S/8 = 256 chunks per row
    float2 st = stats[row];
    s16x8 v = ((const s16x8*)y)[i8];
    float* o = out + i8 * 8;
#pragma unroll
    for (int e = 0; e < 8; ++e) {
        float f = fmaxf(bf2f((unsigned short)v[e]), 0.f);
        o[e] = (f - st.x) * st.y;
    }
}

// ---------------------------------------------------------------------------
extern "C" void kernel_launch(void* const* d_in, const int* in_sizes, int n_in,
                              void* d_out, int out_size, void* d_ws, size_t ws_size,
                              hipStream_t stream) {
    const float* inp = (const float*)d_in[0];
    const float* pos = (const float*)d_in[1];
    const float* divisor = (const float*)d_in[2];
    const float* w[6] = { (const float*)d_in[3], (const float*)d_in[4],
                          (const float*)d_in[5], (const float*)d_in[6],
                          (const float*)d_in[7], (const float*)d_in[8] };
    float* out = (float*)d_out;

    size_t off = 0;
    auto alloc = [&](size_t bytes) {
        off = (off + 255) & ~(size_t)255;
        void* r = (char*)d_ws + off;
        off += bytes;
        return r;
    };

    const size_t needB = ((BSPF_ * 2 + 255) & ~255UL)
                       + ((3 * BSPF_ * 2 + 255) & ~255UL)
                       + ((3 * 7 * FF_ * 2 + 255) & ~255UL)
                       + ((3 * BFS_ * 2 + 255) & ~255UL)
                       + ((3 * BFS_ * 2 + 255) & ~255UL)
                       + ((3 * B_ * F_ * 8 + 255) & ~255UL)
                       + ((B_ * NC_ * S_ * 4 + 255) & ~255UL)
                       + 4096;
    const size_t needC = needB + ((3 * BFS_ * 2 + 255) & ~255UL);   // + split-K partials
    const size_t needD = needC + ((BFS_ * 2 + 255) & ~255UL);       // + bf16 inp copy

    if (ws_size >= needB) {
        const bool splitK = (ws_size >= needC);
        const bool haveInpb = (ws_size >= needD);
        // NOTE: allocation ORDER matters — conv_gemm8's B staging overreads up
        // to 58 rows past a slab end (never consumed); xT overflow lands in
        // hT3, hT3 overflow lands in Wb3. Keep xT -> hT3 -> Wb3 adjacency.
        bf16* xT   = (bf16*)alloc(BSPF_ * 2);
        bf16* hT3  = (bf16*)alloc(3 * BSPF_ * 2);
        bf16* Wb3  = (bf16*)alloc(3 * 7 * FF_ * 2);
        bf16* O3   = (bf16*)alloc(3 * BFS_ * 2);
        bf16* br3  = (bf16*)alloc(3 * BFS_ * 2);
        float2* stats3 = (float2*)alloc(3 * B_ * F_ * 8);
        float* partials = (float*)alloc(B_ * NC_ * S_ * 4);
        bf16* P0 = splitK ? (bf16*)alloc(3 * BFS_ * 2) : nullptr;
        bf16* inpb = haveInpb ? (bf16*)alloc(BFS_ * 2) : nullptr;

        zero_pads<<<(4 * B_ * (K_ - 1) * F_ + 255) / 256, 256, 0, stream>>>(xT, hT3, 3);
        prep_x<<<dim3(S_ / 64, F_ / 64, B_), 256, 0, stream>>>(inp, pos, xT, inpb);

        wconv3<<<dim3(F_ * F_ / 256, 3), 256, 0, stream>>>(w[0], w[2], w[4], Wb3);
        if (splitK) {
            conv_gemm8<true><<<768, 512, 0, stream>>>(Wb3, xT, P0, O3, 7 * FF_, 0, BFS_);
            addb_stats<<<3 * B_ * F_ / 4, 256, 0, stream>>>(P0, O3, stats3);
        } else {
            conv_gemm8<false><<<384, 512, 0, stream>>>(Wb3, xT, O3, O3, 7 * FF_, 0, BFS_);
            rowstats_bf16<<<3 * B_ * F_ / 4, 256, 0, stream>>>(O3, stats3);
        }
        normT<<<dim3(S_ / 64, F_ / 64, 12), 256, 0, stream>>>(O3, stats3, hT3);

        wconv3<<<dim3(F_ * F_ / 256, 3), 256, 0, stream>>>(w[1], w[3], w[5], Wb3);
        if (splitK) {
            conv_gemm8<true><<<768, 512, 0, stream>>>(Wb3, hT3, P0, br3, 7 * FF_, BSPF_, BFS_);
            bf16* ybf = O3;   // O3 dead after normT
            combine_partial2<<<B_ * NC_ * S_ / 256, 256, 0, stream>>>(P0, br3, partials);
            if (haveInpb)
                combine_apply2<<<B_ * NC_ * S_ / 256, 256, 0, stream>>>(
                    inpb, divisor, P0, br3, partials, ybf);
            else
                combine_apply2f<<<B_ * NC_ * S_ / 256, 256, 0, stream>>>(
                    inp, divisor, P0, br3, partials, ybf);
            rowstats_bf16<<<B_ * F_ / 4, 256, 0, stream>>>(ybf, stats3);
            finalnorm_bf<<<(int)(BFS_ / 8 / 256), 256, 0, stream>>>(ybf, stats3, out);
        } else {
            conv_gemm8<false><<<384, 512, 0, stream>>>(Wb3, hT3, br3, br3, 7 * FF_, BSPF_, BFS_);
            float* ybuf = (float*)O3;
            combine_partial<<<B_ * NC_ * S_ / 256, 256, 0, stream>>>(br3, partials);
            combine_apply<<<B_ * NC_ * S_ / 256, 256, 0, stream>>>(
                inp, divisor, br3, br3 + BFS_, br3 + 2 * BFS_, partials, ybuf);
            rowstats_f32<<<B_ * F_ / 4, 256, 0, stream>>>(ybuf, stats3);
            finalnorm<<<(B_ * F_ * S_) / 256, 256, 0, stream>>>(ybuf, stats3, out);
        }
    } else {
        // sequential fallback (compact ws), proven path
        bf16* xT   = (bf16*)alloc(BSPF_ * 2);
        bf16* hT1  = (bf16*)alloc(BSPF_ * 2);
        bf16* Wb1  = (bf16*)alloc(7 * FF_ * 2);
        bf16* O1   = (bf16*)alloc(BFS_ * 2);
        bf16* br3  = (bf16*)alloc(3 * BFS_ * 2);
        float2* stats3 = (float2*)alloc(B_ * F_ * 8);
        float* partials = (float*)alloc(B_ * NC_ * S_ * 4);
        float* ybuf = (float*)xT;

        zero_pads<<<(2 * B_ * (K_ - 1) * F_ + 255) / 256, 256, 0, stream>>>(xT, hT1, 1);
        prep_x<<<dim3(S_ / 64, F_ / 64, B_), 256, 0, stream>>>(inp, pos, xT, nullptr);

        for (int j = 0; j < 3; ++j) {
            wconv<<<F_ * F_ / 256, 256, 0, stream>>>(w[2 * j], Wb1);
            conv_gemm_small<<<16 * 8 * 4, 256, 0, stream>>>(Wb1, xT, O1);
            rowstats_bf16<<<B_ * F_ / 4, 256, 0, stream>>>(O1, stats3);
            normT<<<dim3(S_ / 64, F_ / 64, 4), 256, 0, stream>>>(O1, stats3, hT1);
            wconv<<<F_ * F_ / 256, 256, 0, stream>>>(w[2 * j + 1], Wb1);
            conv_gemm_small<<<16 * 8 * 4, 256, 0, stream>>>(Wb1, hT1, br3 + j * BFS_);
        }
        combine_partial<<<B_ * NC_ * S_ / 256, 256, 0, stream>>>(br3, partials);
        combine_apply<<<B_ * NC_ * S_ / 256, 256, 0, stream>>>(
            inp, divisor, br3, br3 + BFS_, br3 + 2 * BFS_, partials, ybuf);
        rowstats_f32<<<B_ * F_ / 4, 256, 0, stream>>>(ybuf, stats3);
        finalnorm<<<(B_ * F_ * S_) / 256, 256, 0, stream>>>(ybuf, stats3, out);
    }
}